// Round 1
// baseline (1047.429 us; speedup 1.0000x reference)
//
#include <hip/hip_runtime.h>

// Problem constants (from reference)
constexpr int Nn  = 50000;   // nodes
constexpr int Ee  = 800000;  // edges
constexpr int Bb  = 256;     // graphs
constexpr int INF = 32;      // input feature dim
constexpr int Hh  = 96;      // hidden dim
constexpr float BN_EPS = 1e-5f;

// ---------------------------------------------------------------------------
// Edge aggregation: agg[dst[e]] += h[src[e]]  (segment_sum by destination)
// One 32-lane group per edge; lane handles features f = lane, lane+32, lane+64.
// ---------------------------------------------------------------------------
__global__ void agg_kernel(const float* __restrict__ h, const int* __restrict__ src,
                           const int* __restrict__ dst, float* __restrict__ agg, int F) {
    int lane = threadIdx.x & 31;
    long g  = (((long)blockIdx.x * blockDim.x) + threadIdx.x) >> 5;
    long gs = ((long)gridDim.x * blockDim.x) >> 5;
    for (long e = g; e < Ee; e += gs) {
        int s = src[e];
        int d = dst[e];
        const float* hs = h + (long)s * F;
        float* ad = agg + (long)d * F;
        for (int f = lane; f < F; f += 32)
            atomicAdd(&ad[f], hs[f]);
    }
}

// ---------------------------------------------------------------------------
// FC1 + eval-mode BN + ReLU:  out = relu(BN((h+agg) @ w_in + b_in))
// Block = 192 threads = 2 nodes x 96 output features. w_in staged in LDS.
// Safe when out aliases agg (per-node row read fully into LDS before write).
// ---------------------------------------------------------------------------
template<int DIN>
__global__ void fc1_kernel(const float* __restrict__ h, const float* __restrict__ agg,
                           const float* __restrict__ w_in, const float* __restrict__ b_in,
                           const float* __restrict__ gamma, const float* __restrict__ beta,
                           const float* __restrict__ rmean, const float* __restrict__ rvar,
                           float* __restrict__ out) {
    __shared__ float wmat[DIN * Hh];
    __shared__ float vbuf[2][DIN];
    const int j   = threadIdx.x % Hh;   // output feature
    const int sub = threadIdx.x / Hh;   // which of the 2 nodes

    for (int i = threadIdx.x; i < DIN * Hh; i += blockDim.x) wmat[i] = w_in[i];
    const float scale = gamma[j] * rsqrtf(rvar[j] + BN_EPS);
    const float shift = beta[j] - rmean[j] * scale;
    const float bj = b_in[j];
    __syncthreads();

    for (int n0 = blockIdx.x * 2; n0 < Nn; n0 += gridDim.x * 2) {
        const int node = n0 + sub;
        if (node < Nn) {
            const float* hp = h   + (long)node * DIN;
            const float* ap = agg + (long)node * DIN;
            for (int k = j; k < DIN; k += Hh) vbuf[sub][k] = hp[k] + ap[k];
        }
        __syncthreads();
        if (node < Nn) {
            float z = bj;
            #pragma unroll
            for (int k = 0; k < DIN; ++k) z = fmaf(vbuf[sub][k], wmat[k * Hh + j], z);
            z = fmaf(z, scale, shift);          // BN (eval mode)
            out[(long)node * Hh + j] = fmaxf(z, 0.0f);
        }
        __syncthreads();
    }
}

// ---------------------------------------------------------------------------
// FC2 + ReLU: out = relu(z @ w_out + b_out). In-place safe (out may alias zin).
// ---------------------------------------------------------------------------
__global__ void fc2_kernel(const float* __restrict__ zin,
                           const float* __restrict__ w_out, const float* __restrict__ b_out,
                           float* __restrict__ out) {
    __shared__ float wmat[Hh * Hh];
    __shared__ float vbuf[2][Hh];
    const int j   = threadIdx.x % Hh;
    const int sub = threadIdx.x / Hh;

    for (int i = threadIdx.x; i < Hh * Hh; i += blockDim.x) wmat[i] = w_out[i];
    const float bj = b_out[j];
    __syncthreads();

    for (int n0 = blockIdx.x * 2; n0 < Nn; n0 += gridDim.x * 2) {
        const int node = n0 + sub;
        if (node < Nn) vbuf[sub][j] = zin[(long)node * Hh + j];
        __syncthreads();
        if (node < Nn) {
            float o = bj;
            #pragma unroll
            for (int k = 0; k < Hh; ++k) o = fmaf(vbuf[sub][k], wmat[k * Hh + j], o);
            out[(long)node * Hh + j] = fmaxf(o, 0.0f);
        }
        __syncthreads();
    }
}

// ---------------------------------------------------------------------------
// Graph pooling: pooled[batch[n]] += h[n]
// ---------------------------------------------------------------------------
__global__ void pool_kernel(const float* __restrict__ h, const int* __restrict__ batch,
                            float* __restrict__ pooled) {
    int lane = threadIdx.x & 31;
    long g  = (((long)blockIdx.x * blockDim.x) + threadIdx.x) >> 5;
    long gs = ((long)gridDim.x * blockDim.x) >> 5;
    for (long n = g; n < Nn; n += gs) {
        int b = batch[n];
        const float* hp = h + n * Hh;
        float* pp = pooled + (long)b * Hh;
        for (int f = lane; f < Hh; f += 32)
            atomicAdd(&pp[f], hp[f]);
    }
}

// ---------------------------------------------------------------------------
// Head: out[b] = dot(pooled[b], head_w[r_target[b]]) + head_b[r_target[b]]
// One wave per sample.
// ---------------------------------------------------------------------------
__global__ void head_kernel(const float* __restrict__ pooled, const int* __restrict__ rt,
                            const float* __restrict__ hw, const float* __restrict__ hb,
                            float* __restrict__ outv) {
    const int b = blockIdx.x;
    const int lane = threadIdx.x;
    const int t = rt[b];
    const float* pp = pooled + (long)b * Hh;
    const float* wp = hw + (long)t * Hh;
    float s = 0.0f;
    for (int j = lane; j < Hh; j += 64) s += pp[j] * wp[j];
    #pragma unroll
    for (int off = 32; off > 0; off >>= 1) s += __shfl_down(s, off, 64);
    if (lane == 0) outv[b] = s + hb[t];
}

// ---------------------------------------------------------------------------
extern "C" void kernel_launch(void* const* d_in, const int* in_sizes, int n_in,
                              void* d_out, int out_size, void* d_ws, size_t ws_size,
                              hipStream_t stream) {
    const float* x     = (const float*)d_in[0];
    const int*   ei    = (const int*)d_in[1];      // [2, E] flattened (int32 per harness)
    const int*   src   = ei;                       // edge_index[0]
    const int*   dst   = ei + Ee;                  // edge_index[1]
    const int*   batch = (const int*)d_in[2];
    const int*   rt    = (const int*)d_in[3];

    // Per-layer params: w_in, b_in, gamma, beta, rmean, rvar, w_out, b_out
    const float* P[3][8];
    for (int l = 0; l < 3; ++l)
        for (int p = 0; p < 8; ++p)
            P[l][p] = (const float*)d_in[4 + l * 8 + p];
    const float* head_w = (const float*)d_in[28];
    const float* head_b = (const float*)d_in[29];

    float* bufA   = (float*)d_ws;                      // N*H floats
    float* bufB   = bufA + (size_t)Nn * Hh;            // N*H floats
    float* pooled = bufB + (size_t)Nn * Hh;            // B*H floats
    float* out    = (float*)d_out;

    const dim3 blk256(256), blk192(192);
    const int GRID_AGG = 2048, GRID_FC = 2048;

    // ----- Layer 1 (din = 32): h = x, agg -> bufA, out -> bufB -----
    hipMemsetAsync(bufA, 0, (size_t)Nn * INF * sizeof(float), stream);
    agg_kernel<<<GRID_AGG, blk256, 0, stream>>>(x, src, dst, bufA, INF);
    fc1_kernel<INF><<<GRID_FC, blk192, 0, stream>>>(x, bufA,
        P[0][0], P[0][1], P[0][2], P[0][3], P[0][4], P[0][5], bufB);
    fc2_kernel<<<GRID_FC, blk192, 0, stream>>>(bufB, P[0][6], P[0][7], bufB);

    // ----- Layer 2 (din = 96): h = bufB, agg -> bufA, out -> bufA (in place) -----
    hipMemsetAsync(bufA, 0, (size_t)Nn * Hh * sizeof(float), stream);
    agg_kernel<<<GRID_AGG, blk256, 0, stream>>>(bufB, src, dst, bufA, Hh);
    fc1_kernel<Hh><<<GRID_FC, blk192, 0, stream>>>(bufB, bufA,
        P[1][0], P[1][1], P[1][2], P[1][3], P[1][4], P[1][5], bufA);
    fc2_kernel<<<GRID_FC, blk192, 0, stream>>>(bufA, P[1][6], P[1][7], bufA);

    // ----- Layer 3 (din = 96): h = bufA, agg -> bufB, out -> bufB (in place) -----
    hipMemsetAsync(bufB, 0, (size_t)Nn * Hh * sizeof(float), stream);
    agg_kernel<<<GRID_AGG, blk256, 0, stream>>>(bufA, src, dst, bufB, Hh);
    fc1_kernel<Hh><<<GRID_FC, blk192, 0, stream>>>(bufA, bufB,
        P[2][0], P[2][1], P[2][2], P[2][3], P[2][4], P[2][5], bufB);
    fc2_kernel<<<GRID_FC, blk192, 0, stream>>>(bufB, P[2][6], P[2][7], bufB);

    // ----- Pool + head -----
    hipMemsetAsync(pooled, 0, (size_t)Bb * Hh * sizeof(float), stream);
    pool_kernel<<<512, blk256, 0, stream>>>(bufB, batch, pooled);
    head_kernel<<<Bb, 64, 0, stream>>>(pooled, rt, head_w, head_b, out);
}

// Round 2
// 763.987 us; speedup vs baseline: 1.3710x; 1.3710x over previous
//
#include <hip/hip_runtime.h>

// Problem constants (from reference)
constexpr int Nn  = 50000;   // nodes
constexpr int Ee  = 800000;  // edges
constexpr int Bb  = 256;     // graphs
constexpr int INF = 32;      // input feature dim
constexpr int Hh  = 96;      // hidden dim
constexpr float BN_EPS = 1e-5f;

// ---------------------------------------------------------------------------
// CSR build: deg count -> exclusive scan -> cursor copy -> scatter
// ---------------------------------------------------------------------------
__global__ void count_deg_kernel(const int* __restrict__ dst, int* __restrict__ deg) {
    for (long e = (long)blockIdx.x * blockDim.x + threadIdx.x; e < Ee;
         e += (long)gridDim.x * blockDim.x)
        atomicAdd(&deg[dst[e]], 1);
}

// Single-block exclusive scan of deg[0..N) -> rowptr[0..N], rowptr[N] = E.
__global__ void scan_offsets_kernel(const int* __restrict__ deg, int* __restrict__ rowptr) {
    constexpr int T = 1024;
    constexpr int CHUNK = (Nn + T - 1) / T;   // 49
    __shared__ int ps[T];
    const int t = threadIdx.x;
    const int base = t * CHUNK;
    int sum = 0;
    for (int i = 0; i < CHUNK; ++i) {
        int idx = base + i;
        if (idx < Nn) sum += deg[idx];
    }
    ps[t] = sum;
    __syncthreads();
    for (int d = 1; d < T; d <<= 1) {          // Hillis-Steele inclusive scan
        int v = (t >= d) ? ps[t - d] : 0;
        __syncthreads();
        if (t >= d) ps[t] += v;
        __syncthreads();
    }
    int run = (t == 0) ? 0 : ps[t - 1];        // exclusive prefix for this chunk
    for (int i = 0; i < CHUNK; ++i) {
        int idx = base + i;
        if (idx < Nn) { rowptr[idx] = run; run += deg[idx]; }
    }
    if (t == T - 1) rowptr[Nn] = run;
}

__global__ void copy_cursor_kernel(const int* __restrict__ rowptr, int* __restrict__ cursor) {
    for (int i = blockIdx.x * blockDim.x + threadIdx.x; i < Nn;
         i += gridDim.x * blockDim.x)
        cursor[i] = rowptr[i];
}

__global__ void scatter_csr_kernel(const int* __restrict__ src, const int* __restrict__ dst,
                                   int* __restrict__ cursor, int* __restrict__ csr) {
    for (long e = (long)blockIdx.x * blockDim.x + threadIdx.x; e < Ee;
         e += (long)gridDim.x * blockDim.x) {
        int d = dst[e];
        int p = atomicAdd(&cursor[d], 1);
        csr[p] = src[e];
    }
}

// ---------------------------------------------------------------------------
// CSR aggregation with self term: out[i] = h[i] + sum_{j in N(i)} h[j]
// One group of F/4 threads per node, float4 per thread. No atomics.
// ---------------------------------------------------------------------------
template<int F>
__global__ void agg_csr_kernel(const float* __restrict__ h, const int* __restrict__ rowptr,
                               const int* __restrict__ csr, float* __restrict__ out) {
    constexpr int V = F / 4;                    // threads per node
    const int gpb = blockDim.x / V;             // node groups per block
    const int g = threadIdx.x / V;
    const int j = threadIdx.x % V;
    const float4* h4 = (const float4*)h;
    float4* out4 = (float4*)out;

    for (long node = (long)blockIdx.x * gpb + g; node < Nn; node += (long)gridDim.x * gpb) {
        const int e0 = rowptr[node];
        const int e1 = rowptr[node + 1];
        float4 acc = h4[node * V + j];          // self term
        for (int e = e0; e < e1; ++e) {
            const long s = csr[e];
            const float4 v = h4[s * V + j];
            acc.x += v.x; acc.y += v.y; acc.z += v.z; acc.w += v.w;
        }
        out4[node * V + j] = acc;
    }
}

// ---------------------------------------------------------------------------
// FC1 + eval-mode BN + ReLU:  out = relu(BN(xin @ w_in + b_in))
// xin is the already-combined (h + agg) row. In-place safe (out may alias xin).
// ---------------------------------------------------------------------------
template<int DIN>
__global__ void fc1_kernel(const float* __restrict__ xin,
                           const float* __restrict__ w_in, const float* __restrict__ b_in,
                           const float* __restrict__ gamma, const float* __restrict__ beta,
                           const float* __restrict__ rmean, const float* __restrict__ rvar,
                           float* __restrict__ out) {
    __shared__ float wmat[DIN * Hh];
    __shared__ float vbuf[2][DIN];
    const int j   = threadIdx.x % Hh;   // output feature
    const int sub = threadIdx.x / Hh;   // which of the 2 nodes

    for (int i = threadIdx.x; i < DIN * Hh; i += blockDim.x) wmat[i] = w_in[i];
    const float scale = gamma[j] * rsqrtf(rvar[j] + BN_EPS);
    const float shift = beta[j] - rmean[j] * scale;
    const float bj = b_in[j];
    __syncthreads();

    for (int n0 = blockIdx.x * 2; n0 < Nn; n0 += gridDim.x * 2) {
        const int node = n0 + sub;
        if (node < Nn) {
            const float* xp = xin + (long)node * DIN;
            for (int k = j; k < DIN; k += Hh) vbuf[sub][k] = xp[k];
        }
        __syncthreads();
        if (node < Nn) {
            float z = bj;
            #pragma unroll
            for (int k = 0; k < DIN; ++k) z = fmaf(vbuf[sub][k], wmat[k * Hh + j], z);
            z = fmaf(z, scale, shift);          // BN (eval mode)
            out[(long)node * Hh + j] = fmaxf(z, 0.0f);
        }
        __syncthreads();
    }
}

// ---------------------------------------------------------------------------
// FC2 + ReLU: out = relu(z @ w_out + b_out). In-place safe.
// ---------------------------------------------------------------------------
__global__ void fc2_kernel(const float* __restrict__ zin,
                           const float* __restrict__ w_out, const float* __restrict__ b_out,
                           float* __restrict__ out) {
    __shared__ float wmat[Hh * Hh];
    __shared__ float vbuf[2][Hh];
    const int j   = threadIdx.x % Hh;
    const int sub = threadIdx.x / Hh;

    for (int i = threadIdx.x; i < Hh * Hh; i += blockDim.x) wmat[i] = w_out[i];
    const float bj = b_out[j];
    __syncthreads();

    for (int n0 = blockIdx.x * 2; n0 < Nn; n0 += gridDim.x * 2) {
        const int node = n0 + sub;
        if (node < Nn) vbuf[sub][j] = zin[(long)node * Hh + j];
        __syncthreads();
        if (node < Nn) {
            float o = bj;
            #pragma unroll
            for (int k = 0; k < Hh; ++k) o = fmaf(vbuf[sub][k], wmat[k * Hh + j], o);
            out[(long)node * Hh + j] = fmaxf(o, 0.0f);
        }
        __syncthreads();
    }
}

// ---------------------------------------------------------------------------
// Graph pooling: pooled[batch[n]] += h[n]  (atomic; only 19 MB of traffic)
// ---------------------------------------------------------------------------
__global__ void pool_kernel(const float* __restrict__ h, const int* __restrict__ batch,
                            float* __restrict__ pooled) {
    int lane = threadIdx.x & 31;
    long g  = (((long)blockIdx.x * blockDim.x) + threadIdx.x) >> 5;
    long gs = ((long)gridDim.x * blockDim.x) >> 5;
    for (long n = g; n < Nn; n += gs) {
        int b = batch[n];
        const float* hp = h + n * Hh;
        float* pp = pooled + (long)b * Hh;
        for (int f = lane; f < Hh; f += 32)
            atomicAdd(&pp[f], hp[f]);
    }
}

// ---------------------------------------------------------------------------
// Head: out[b] = dot(pooled[b], head_w[r_target[b]]) + head_b[r_target[b]]
// ---------------------------------------------------------------------------
__global__ void head_kernel(const float* __restrict__ pooled, const int* __restrict__ rt,
                            const float* __restrict__ hw, const float* __restrict__ hb,
                            float* __restrict__ outv) {
    const int b = blockIdx.x;
    const int lane = threadIdx.x;
    const int t = rt[b];
    const float* pp = pooled + (long)b * Hh;
    const float* wp = hw + (long)t * Hh;
    float s = 0.0f;
    for (int j = lane; j < Hh; j += 64) s += pp[j] * wp[j];
    #pragma unroll
    for (int off = 32; off > 0; off >>= 1) s += __shfl_down(s, off, 64);
    if (lane == 0) outv[b] = s + hb[t];
}

// ---------------------------------------------------------------------------
extern "C" void kernel_launch(void* const* d_in, const int* in_sizes, int n_in,
                              void* d_out, int out_size, void* d_ws, size_t ws_size,
                              hipStream_t stream) {
    const float* x     = (const float*)d_in[0];
    const int*   ei    = (const int*)d_in[1];      // [2, E] flattened int32
    const int*   src   = ei;                       // edge_index[0]
    const int*   dst   = ei + Ee;                  // edge_index[1]
    const int*   batch = (const int*)d_in[2];
    const int*   rt    = (const int*)d_in[3];

    const float* P[3][8];
    for (int l = 0; l < 3; ++l)
        for (int p = 0; p < 8; ++p)
            P[l][p] = (const float*)d_in[4 + l * 8 + p];
    const float* head_w = (const float*)d_in[28];
    const float* head_b = (const float*)d_in[29];

    // Workspace layout
    float* bufA   = (float*)d_ws;                        // N*H floats
    float* bufB   = bufA + (size_t)Nn * Hh;              // N*H floats
    float* pooled = bufB + (size_t)Nn * Hh;              // B*H floats
    int*   deg    = (int*)(pooled + (size_t)Bb * Hh);    // N ints
    int*   rowptr = deg + Nn;                            // N+1 ints
    int*   cursor = rowptr + Nn + 1;                     // N ints
    int*   csr    = cursor + Nn;                         // E ints
    float* out    = (float*)d_out;

    const dim3 blk256(256), blk192(192);
    const int GRID_E = 1024, GRID_FC = 2048;

    // ----- Build CSR (dst -> srcs), once per launch -----
    hipMemsetAsync(deg, 0, Nn * sizeof(int), stream);
    count_deg_kernel<<<GRID_E, blk256, 0, stream>>>(dst, deg);
    scan_offsets_kernel<<<1, 1024, 0, stream>>>(deg, rowptr);
    copy_cursor_kernel<<<128, blk256, 0, stream>>>(rowptr, cursor);
    scatter_csr_kernel<<<GRID_E, blk256, 0, stream>>>(src, dst, cursor, csr);

    // ----- Layer 1 (din = 32): agg(x) -> bufA, fc1 -> bufB, fc2 in place -----
    agg_csr_kernel<INF><<<1563, blk256, 0, stream>>>(x, rowptr, csr, bufA);
    fc1_kernel<INF><<<GRID_FC, blk192, 0, stream>>>(bufA,
        P[0][0], P[0][1], P[0][2], P[0][3], P[0][4], P[0][5], bufB);
    fc2_kernel<<<GRID_FC, blk192, 0, stream>>>(bufB, P[0][6], P[0][7], bufB);

    // ----- Layer 2 (din = 96): agg(bufB) -> bufA, fc1/fc2 in place -----
    agg_csr_kernel<Hh><<<6250, blk192, 0, stream>>>(bufB, rowptr, csr, bufA);
    fc1_kernel<Hh><<<GRID_FC, blk192, 0, stream>>>(bufA,
        P[1][0], P[1][1], P[1][2], P[1][3], P[1][4], P[1][5], bufA);
    fc2_kernel<<<GRID_FC, blk192, 0, stream>>>(bufA, P[1][6], P[1][7], bufA);

    // ----- Layer 3 (din = 96): agg(bufA) -> bufB, fc1/fc2 in place -----
    agg_csr_kernel<Hh><<<6250, blk192, 0, stream>>>(bufA, rowptr, csr, bufB);
    fc1_kernel<Hh><<<GRID_FC, blk192, 0, stream>>>(bufB,
        P[2][0], P[2][1], P[2][2], P[2][3], P[2][4], P[2][5], bufB);
    fc2_kernel<<<GRID_FC, blk192, 0, stream>>>(bufB, P[2][6], P[2][7], bufB);

    // ----- Pool + head -----
    hipMemsetAsync(pooled, 0, (size_t)Bb * Hh * sizeof(float), stream);
    pool_kernel<<<512, blk256, 0, stream>>>(bufB, batch, pooled);
    head_kernel<<<Bb, 64, 0, stream>>>(pooled, rt, head_w, head_b, out);
}

// Round 3
// 662.343 us; speedup vs baseline: 1.5814x; 1.1535x over previous
//
#include <hip/hip_runtime.h>

// Problem constants (from reference)
constexpr int Nn  = 50000;   // nodes
constexpr int Ee  = 800000;  // edges
constexpr int Bb  = 256;     // graphs
constexpr int INF = 32;      // input feature dim
constexpr int Hh  = 96;      // hidden dim
constexpr float BN_EPS = 1e-5f;

constexpr int SCAN_BLK  = 256;
constexpr int SCAN_NBLK = (Nn + SCAN_BLK - 1) / SCAN_BLK;   // 196

// ---------------------------------------------------------------------------
// CSR build: deg count -> hierarchical scan -> scatter
// ---------------------------------------------------------------------------
__global__ void count_deg_kernel(const int* __restrict__ dst, int* __restrict__ deg) {
    for (long e = (long)blockIdx.x * blockDim.x + threadIdx.x; e < Ee;
         e += (long)gridDim.x * blockDim.x)
        atomicAdd(&deg[dst[e]], 1);
}

// Phase 1: per-block sums of deg (SCAN_BLK elems per block)
__global__ void block_sum_kernel(const int* __restrict__ deg, int* __restrict__ partial) {
    const int t = threadIdx.x;
    const int idx = blockIdx.x * SCAN_BLK + t;
    int v = (idx < Nn) ? deg[idx] : 0;
    #pragma unroll
    for (int off = 32; off > 0; off >>= 1) v += __shfl_down(v, off, 64);
    __shared__ int ws[SCAN_BLK / 64];
    if ((t & 63) == 0) ws[t >> 6] = v;
    __syncthreads();
    if (t == 0) {
        int s = 0;
        #pragma unroll
        for (int w = 0; w < SCAN_BLK / 64; ++w) s += ws[w];
        partial[blockIdx.x] = s;
    }
}

// Phase 2: single-block exclusive scan of the SCAN_NBLK partial sums
__global__ void scan_partial_kernel(const int* __restrict__ partial, int* __restrict__ blockpref) {
    __shared__ int ps[256];
    const int t = threadIdx.x;
    ps[t] = (t < SCAN_NBLK) ? partial[t] : 0;
    __syncthreads();
    for (int d = 1; d < 256; d <<= 1) {
        int u = (t >= d) ? ps[t - d] : 0;
        __syncthreads();
        if (t >= d) ps[t] += u;
        __syncthreads();
    }
    if (t < SCAN_NBLK) blockpref[t] = (t == 0) ? 0 : ps[t - 1];
}

// Phase 3: block-local exclusive scan + block prefix -> rowptr & cursor
__global__ void scan_apply_kernel(const int* __restrict__ deg, const int* __restrict__ blockpref,
                                  int* __restrict__ rowptr, int* __restrict__ cursor) {
    __shared__ int ps[SCAN_BLK];
    const int t = threadIdx.x;
    const int idx = blockIdx.x * SCAN_BLK + t;
    const int v = (idx < Nn) ? deg[idx] : 0;
    ps[t] = v;
    __syncthreads();
    for (int d = 1; d < SCAN_BLK; d <<= 1) {
        int u = (t >= d) ? ps[t - d] : 0;
        __syncthreads();
        if (t >= d) ps[t] += u;
        __syncthreads();
    }
    if (idx < Nn) {
        int r = blockpref[blockIdx.x] + ps[t] - v;   // exclusive
        rowptr[idx] = r;
        cursor[idx] = r;
    }
    if (idx == Nn - 1) rowptr[Nn] = Ee;
}

__global__ void scatter_csr_kernel(const int* __restrict__ src, const int* __restrict__ dst,
                                   int* __restrict__ cursor, int* __restrict__ csr) {
    for (long e = (long)blockIdx.x * blockDim.x + threadIdx.x; e < Ee;
         e += (long)gridDim.x * blockDim.x) {
        int d = dst[e];
        int p = atomicAdd(&cursor[d], 1);
        csr[p] = src[e];
    }
}

// ---------------------------------------------------------------------------
// CSR aggregation with self term: out[i] = h[i] + sum_{j in N(i)} h[j]
// One group of F/4 threads per node, float4 per thread. No atomics.
// ---------------------------------------------------------------------------
template<int F>
__global__ void agg_csr_kernel(const float* __restrict__ h, const int* __restrict__ rowptr,
                               const int* __restrict__ csr, float* __restrict__ out) {
    constexpr int V = F / 4;                    // threads per node
    const int gpb = blockDim.x / V;             // node groups per block
    const int g = threadIdx.x / V;
    const int j = threadIdx.x % V;
    const float4* h4 = (const float4*)h;
    float4* out4 = (float4*)out;

    for (long node = (long)blockIdx.x * gpb + g; node < Nn; node += (long)gridDim.x * gpb) {
        const int e0 = rowptr[node];
        const int e1 = rowptr[node + 1];
        float4 acc = h4[node * V + j];          // self term
        for (int e = e0; e < e1; ++e) {
            const long s = csr[e];
            const float4 v = h4[s * V + j];
            acc.x += v.x; acc.y += v.y; acc.z += v.z; acc.w += v.w;
        }
        out4[node * V + j] = acc;
    }
}

// ---------------------------------------------------------------------------
// FC1 + eval-mode BN + ReLU:  out = relu(BN(xin @ w_in + b_in))
// xin is the already-combined (h + agg) row. In-place safe (out may alias xin).
// ---------------------------------------------------------------------------
template<int DIN>
__global__ void fc1_kernel(const float* __restrict__ xin,
                           const float* __restrict__ w_in, const float* __restrict__ b_in,
                           const float* __restrict__ gamma, const float* __restrict__ beta,
                           const float* __restrict__ rmean, const float* __restrict__ rvar,
                           float* __restrict__ out) {
    __shared__ float wmat[DIN * Hh];
    __shared__ float vbuf[2][DIN];
    const int j   = threadIdx.x % Hh;   // output feature
    const int sub = threadIdx.x / Hh;   // which of the 2 nodes

    for (int i = threadIdx.x; i < DIN * Hh; i += blockDim.x) wmat[i] = w_in[i];
    const float scale = gamma[j] * rsqrtf(rvar[j] + BN_EPS);
    const float shift = beta[j] - rmean[j] * scale;
    const float bj = b_in[j];
    __syncthreads();

    for (int n0 = blockIdx.x * 2; n0 < Nn; n0 += gridDim.x * 2) {
        const int node = n0 + sub;
        if (node < Nn) {
            const float* xp = xin + (long)node * DIN;
            for (int k = j; k < DIN; k += Hh) vbuf[sub][k] = xp[k];
        }
        __syncthreads();
        if (node < Nn) {
            float z = bj;
            #pragma unroll
            for (int k = 0; k < DIN; ++k) z = fmaf(vbuf[sub][k], wmat[k * Hh + j], z);
            z = fmaf(z, scale, shift);          // BN (eval mode)
            out[(long)node * Hh + j] = fmaxf(z, 0.0f);
        }
        __syncthreads();
    }
}

// ---------------------------------------------------------------------------
// FC2 + ReLU: out = relu(z @ w_out + b_out). In-place safe.
// ---------------------------------------------------------------------------
__global__ void fc2_kernel(const float* __restrict__ zin,
                           const float* __restrict__ w_out, const float* __restrict__ b_out,
                           float* __restrict__ out) {
    __shared__ float wmat[Hh * Hh];
    __shared__ float vbuf[2][Hh];
    const int j   = threadIdx.x % Hh;
    const int sub = threadIdx.x / Hh;

    for (int i = threadIdx.x; i < Hh * Hh; i += blockDim.x) wmat[i] = w_out[i];
    const float bj = b_out[j];
    __syncthreads();

    for (int n0 = blockIdx.x * 2; n0 < Nn; n0 += gridDim.x * 2) {
        const int node = n0 + sub;
        if (node < Nn) vbuf[sub][j] = zin[(long)node * Hh + j];
        __syncthreads();
        if (node < Nn) {
            float o = bj;
            #pragma unroll
            for (int k = 0; k < Hh; ++k) o = fmaf(vbuf[sub][k], wmat[k * Hh + j], o);
            out[(long)node * Hh + j] = fmaxf(o, 0.0f);
        }
        __syncthreads();
    }
}

// ---------------------------------------------------------------------------
// Fused pool + head. batch is SORTED, so each graph owns a contiguous node
// range found by binary search. No atomics, no pooled buffer needed.
// out[b] = dot(sum_{n in graph b} h[n], head_w[rt[b]]) + head_b[rt[b]]
// One block (96 threads) per graph.
// ---------------------------------------------------------------------------
__global__ void pool_head_kernel(const float* __restrict__ h, const int* __restrict__ batch,
                                 const int* __restrict__ rt, const float* __restrict__ hw,
                                 const float* __restrict__ hb, float* __restrict__ outv) {
    const int b = blockIdx.x;
    const int j = threadIdx.x;       // 0..95

    // start = lower_bound(batch, b), end = lower_bound(batch, b+1)
    int lo = 0, hi = Nn;
    while (lo < hi) { int mid = (lo + hi) >> 1; if (batch[mid] < b) lo = mid + 1; else hi = mid; }
    const int start = lo;
    lo = 0; hi = Nn;
    while (lo < hi) { int mid = (lo + hi) >> 1; if (batch[mid] < b + 1) lo = mid + 1; else hi = mid; }
    const int end = lo;

    float acc = 0.0f;
    for (int n = start; n < end; ++n) acc += h[(long)n * Hh + j];

    const int t = rt[b];
    __shared__ float red[Hh];
    red[j] = acc * hw[(long)t * Hh + j];
    __syncthreads();
    if (j < 32) red[j] += red[j + 64];
    __syncthreads();
    if (j < 32) red[j] += red[j + 32];
    __syncthreads();
    if (j < 32) {
        float s = red[j];
        #pragma unroll
        for (int off = 16; off > 0; off >>= 1) s += __shfl_down(s, off, 64);
        if (j == 0) outv[b] = s + hb[t];
    }
}

// ---------------------------------------------------------------------------
extern "C" void kernel_launch(void* const* d_in, const int* in_sizes, int n_in,
                              void* d_out, int out_size, void* d_ws, size_t ws_size,
                              hipStream_t stream) {
    const float* x     = (const float*)d_in[0];
    const int*   ei    = (const int*)d_in[1];      // [2, E] flattened int32
    const int*   src   = ei;                       // edge_index[0]
    const int*   dst   = ei + Ee;                  // edge_index[1]
    const int*   batch = (const int*)d_in[2];
    const int*   rt    = (const int*)d_in[3];

    const float* P[3][8];
    for (int l = 0; l < 3; ++l)
        for (int p = 0; p < 8; ++p)
            P[l][p] = (const float*)d_in[4 + l * 8 + p];
    const float* head_w = (const float*)d_in[28];
    const float* head_b = (const float*)d_in[29];

    // Workspace layout
    float* bufA    = (float*)d_ws;                       // N*H floats
    float* bufB    = bufA + (size_t)Nn * Hh;             // N*H floats
    int*   deg     = (int*)(bufB + (size_t)Nn * Hh);     // N ints
    int*   rowptr  = deg + Nn;                           // N+1 ints
    int*   cursor  = rowptr + Nn + 1;                    // N ints
    int*   partial = cursor + Nn;                        // SCAN_NBLK ints
    int*   blockpref = partial + SCAN_NBLK;              // SCAN_NBLK ints
    int*   csr     = blockpref + SCAN_NBLK;              // E ints
    float* out     = (float*)d_out;

    const dim3 blk256(256), blk192(192);
    const int GRID_E = 1024, GRID_FC = 2048;

    // ----- Build CSR (dst -> srcs) -----
    hipMemsetAsync(deg, 0, Nn * sizeof(int), stream);
    count_deg_kernel<<<GRID_E, blk256, 0, stream>>>(dst, deg);
    block_sum_kernel<<<SCAN_NBLK, SCAN_BLK, 0, stream>>>(deg, partial);
    scan_partial_kernel<<<1, 256, 0, stream>>>(partial, blockpref);
    scan_apply_kernel<<<SCAN_NBLK, SCAN_BLK, 0, stream>>>(deg, blockpref, rowptr, cursor);
    scatter_csr_kernel<<<GRID_E, blk256, 0, stream>>>(src, dst, cursor, csr);

    // ----- Layer 1 (din = 32): agg(x) -> bufA, fc1 -> bufB, fc2 in place -----
    agg_csr_kernel<INF><<<1563, blk256, 0, stream>>>(x, rowptr, csr, bufA);
    fc1_kernel<INF><<<GRID_FC, blk192, 0, stream>>>(bufA,
        P[0][0], P[0][1], P[0][2], P[0][3], P[0][4], P[0][5], bufB);
    fc2_kernel<<<GRID_FC, blk192, 0, stream>>>(bufB, P[0][6], P[0][7], bufB);

    // ----- Layer 2 (din = 96): agg(bufB) -> bufA, fc1/fc2 in place -----
    agg_csr_kernel<Hh><<<6250, blk192, 0, stream>>>(bufB, rowptr, csr, bufA);
    fc1_kernel<Hh><<<GRID_FC, blk192, 0, stream>>>(bufA,
        P[1][0], P[1][1], P[1][2], P[1][3], P[1][4], P[1][5], bufA);
    fc2_kernel<<<GRID_FC, blk192, 0, stream>>>(bufA, P[1][6], P[1][7], bufA);

    // ----- Layer 3 (din = 96): agg(bufA) -> bufB, fc1/fc2 in place -----
    agg_csr_kernel<Hh><<<6250, blk192, 0, stream>>>(bufA, rowptr, csr, bufB);
    fc1_kernel<Hh><<<GRID_FC, blk192, 0, stream>>>(bufB,
        P[2][0], P[2][1], P[2][2], P[2][3], P[2][4], P[2][5], bufB);
    fc2_kernel<<<GRID_FC, blk192, 0, stream>>>(bufB, P[2][6], P[2][7], bufB);

    // ----- Fused pool + head -----
    pool_head_kernel<<<Bb, Hh, 0, stream>>>(bufB, batch, rt, head_w, head_b, out);
}

// Round 4
// 419.003 us; speedup vs baseline: 2.4998x; 1.5808x over previous
//
#include <hip/hip_runtime.h>

// Problem constants (from reference)
constexpr int Nn  = 50000;   // nodes
constexpr int Ee  = 800000;  // edges
constexpr int Bb  = 256;     // graphs
constexpr int INF = 32;      // input feature dim
constexpr int Hh  = 96;      // hidden dim
constexpr float BN_EPS = 1e-5f;

constexpr int SCAN_BLK  = 256;
constexpr int SCAN_NBLK = (Nn + SCAN_BLK - 1) / SCAN_BLK;   // 196

// ---------------------------------------------------------------------------
// CSR build: deg count -> hierarchical scan -> scatter
// ---------------------------------------------------------------------------
__global__ void count_deg_kernel(const int* __restrict__ dst, int* __restrict__ deg) {
    for (long e = (long)blockIdx.x * blockDim.x + threadIdx.x; e < Ee;
         e += (long)gridDim.x * blockDim.x)
        atomicAdd(&deg[dst[e]], 1);
}

__global__ void block_sum_kernel(const int* __restrict__ deg, int* __restrict__ partial) {
    const int t = threadIdx.x;
    const int idx = blockIdx.x * SCAN_BLK + t;
    int v = (idx < Nn) ? deg[idx] : 0;
    #pragma unroll
    for (int off = 32; off > 0; off >>= 1) v += __shfl_down(v, off, 64);
    __shared__ int ws[SCAN_BLK / 64];
    if ((t & 63) == 0) ws[t >> 6] = v;
    __syncthreads();
    if (t == 0) {
        int s = 0;
        #pragma unroll
        for (int w = 0; w < SCAN_BLK / 64; ++w) s += ws[w];
        partial[blockIdx.x] = s;
    }
}

__global__ void scan_partial_kernel(const int* __restrict__ partial, int* __restrict__ blockpref) {
    __shared__ int ps[256];
    const int t = threadIdx.x;
    ps[t] = (t < SCAN_NBLK) ? partial[t] : 0;
    __syncthreads();
    for (int d = 1; d < 256; d <<= 1) {
        int u = (t >= d) ? ps[t - d] : 0;
        __syncthreads();
        if (t >= d) ps[t] += u;
        __syncthreads();
    }
    if (t < SCAN_NBLK) blockpref[t] = (t == 0) ? 0 : ps[t - 1];
}

__global__ void scan_apply_kernel(const int* __restrict__ deg, const int* __restrict__ blockpref,
                                  int* __restrict__ rowptr, int* __restrict__ cursor) {
    __shared__ int ps[SCAN_BLK];
    const int t = threadIdx.x;
    const int idx = blockIdx.x * SCAN_BLK + t;
    const int v = (idx < Nn) ? deg[idx] : 0;
    ps[t] = v;
    __syncthreads();
    for (int d = 1; d < SCAN_BLK; d <<= 1) {
        int u = (t >= d) ? ps[t - d] : 0;
        __syncthreads();
        if (t >= d) ps[t] += u;
        __syncthreads();
    }
    if (idx < Nn) {
        int r = blockpref[blockIdx.x] + ps[t] - v;   // exclusive
        rowptr[idx] = r;
        cursor[idx] = r;
    }
    if (idx == Nn - 1) rowptr[Nn] = Ee;
}

__global__ void scatter_csr_kernel(const int* __restrict__ src, const int* __restrict__ dst,
                                   int* __restrict__ cursor, int* __restrict__ csr) {
    for (long e = (long)blockIdx.x * blockDim.x + threadIdx.x; e < Ee;
         e += (long)gridDim.x * blockDim.x) {
        int d = dst[e];
        int p = atomicAdd(&cursor[d], 1);
        csr[p] = src[e];
    }
}

// ---------------------------------------------------------------------------
// CSR aggregation with self term: out[i] = h[i] + sum_{j in N(i)} h[j]
// One group of F/4 threads per node, float4 per thread. No atomics.
// ---------------------------------------------------------------------------
template<int F>
__global__ void agg_csr_kernel(const float* __restrict__ h, const int* __restrict__ rowptr,
                               const int* __restrict__ csr, float* __restrict__ out) {
    constexpr int V = F / 4;                    // threads per node
    const int gpb = blockDim.x / V;             // node groups per block
    const int g = threadIdx.x / V;
    const int j = threadIdx.x % V;
    const float4* h4 = (const float4*)h;
    float4* out4 = (float4*)out;

    for (long node = (long)blockIdx.x * gpb + g; node < Nn; node += (long)gridDim.x * gpb) {
        const int e0 = rowptr[node];
        const int e1 = rowptr[node + 1];
        float4 acc = h4[node * V + j];          // self term
        for (int e = e0; e < e1; ++e) {
            const long s = csr[e];
            const float4 v = h4[s * V + j];
            acc.x += v.x; acc.y += v.y; acc.z += v.z; acc.w += v.w;
        }
        out4[node * V + j] = acc;
    }
}

// ---------------------------------------------------------------------------
// Register-blocked FC: out = relu(A[j] * (xin @ w)[n,j] + C[j])
//   BN=true : A = gamma*rsqrt(var+eps), C = (b_in - rmean)*A + beta   (FC1+BN)
//   BN=false: A = 1, C = b_out                                        (FC2)
// Block = 256 threads -> 64-node x 96-feature tile; thread = 4 nodes x 6 feats.
// In-place safe: block stages its 64 rows into LDS before overwriting them.
// ---------------------------------------------------------------------------
template<int DIN, bool BN>
__global__ __launch_bounds__(256)
void fc_kernel(const float* __restrict__ xin, const float* __restrict__ w,
               const float* __restrict__ p0,      // BN ? b_in : b_out
               const float* __restrict__ gamma, const float* __restrict__ beta,
               const float* __restrict__ rmean, const float* __restrict__ rvar,
               float* __restrict__ out) {
    constexpr int XST = DIN + 4;                  // pad: avoids row-stride bank alias
    constexpr int C4  = DIN / 4;
    __shared__ float ws[DIN * Hh];
    __shared__ float xs[64 * XST];

    const int tid = threadIdx.x;
    const int jt  = tid & 15;                     // 16 feature groups x 6
    const int nt  = tid >> 4;                     // 16 node groups x 4
    const int j0  = jt * 6;
    const int nbase = blockIdx.x * 64;

    // stage W [DIN x 96] via float4
    for (int i = tid * 4; i < DIN * Hh; i += 1024)
        *(float4*)&ws[i] = *(const float4*)&w[i];

    // stage x tile [64 x DIN] via float4, zero-padded past Nn
    for (int idx = tid; idx < 64 * C4; idx += 256) {
        const int r = idx / C4, c4 = idx % C4;
        const int gr = nbase + r;
        float4 v = make_float4(0.f, 0.f, 0.f, 0.f);
        if (gr < Nn) v = *(const float4*)&xin[(long)gr * DIN + c4 * 4];
        *(float4*)&xs[r * XST + c4 * 4] = v;
    }

    // per-thread epilogue constants
    float A[6], C[6];
    #pragma unroll
    for (int ji = 0; ji < 6; ++ji) {
        const int j = j0 + ji;
        if (BN) {
            const float s = gamma[j] * rsqrtf(rvar[j] + BN_EPS);
            A[ji] = s;
            C[ji] = (p0[j] - rmean[j]) * s + beta[j];
        } else {
            A[ji] = 1.0f;
            C[ji] = p0[j];
        }
    }
    __syncthreads();

    float acc[4][6] = {};
    #pragma unroll 4
    for (int k = 0; k < DIN; ++k) {
        float xv[4];
        #pragma unroll
        for (int ni = 0; ni < 4; ++ni) xv[ni] = xs[(nt * 4 + ni) * XST + k];
        float wv[6];
        #pragma unroll
        for (int q = 0; q < 3; ++q) {
            const float2 t = *(const float2*)&ws[k * Hh + j0 + 2 * q];
            wv[2 * q] = t.x; wv[2 * q + 1] = t.y;
        }
        #pragma unroll
        for (int ni = 0; ni < 4; ++ni)
            #pragma unroll
            for (int ji = 0; ji < 6; ++ji)
                acc[ni][ji] = fmaf(xv[ni], wv[ji], acc[ni][ji]);
    }

    #pragma unroll
    for (int ni = 0; ni < 4; ++ni) {
        const int node = nbase + nt * 4 + ni;
        if (node < Nn) {
            float* op = out + (long)node * Hh + j0;
            #pragma unroll
            for (int q = 0; q < 3; ++q) {
                float2 st;
                st.x = fmaxf(fmaf(acc[ni][2 * q],     A[2 * q],     C[2 * q]),     0.0f);
                st.y = fmaxf(fmaf(acc[ni][2 * q + 1], A[2 * q + 1], C[2 * q + 1]), 0.0f);
                *(float2*)&op[2 * q] = st;
            }
        }
    }
}

// ---------------------------------------------------------------------------
// Fused pool + head (batch sorted -> binary-search node range, no atomics)
// ---------------------------------------------------------------------------
__global__ void pool_head_kernel(const float* __restrict__ h, const int* __restrict__ batch,
                                 const int* __restrict__ rt, const float* __restrict__ hw,
                                 const float* __restrict__ hb, float* __restrict__ outv) {
    const int b = blockIdx.x;
    const int j = threadIdx.x;       // 0..95

    int lo = 0, hi = Nn;
    while (lo < hi) { int mid = (lo + hi) >> 1; if (batch[mid] < b) lo = mid + 1; else hi = mid; }
    const int start = lo;
    lo = 0; hi = Nn;
    while (lo < hi) { int mid = (lo + hi) >> 1; if (batch[mid] < b + 1) lo = mid + 1; else hi = mid; }
    const int end = lo;

    float acc = 0.0f;
    for (int n = start; n < end; ++n) acc += h[(long)n * Hh + j];

    const int t = rt[b];
    __shared__ float red[Hh];
    red[j] = acc * hw[(long)t * Hh + j];
    __syncthreads();
    if (j < 32) red[j] += red[j + 64];
    __syncthreads();
    if (j < 32) red[j] += red[j + 32];
    __syncthreads();
    if (j < 32) {
        float s = red[j];
        #pragma unroll
        for (int off = 16; off > 0; off >>= 1) s += __shfl_down(s, off, 64);
        if (j == 0) outv[b] = s + hb[t];
    }
}

// ---------------------------------------------------------------------------
extern "C" void kernel_launch(void* const* d_in, const int* in_sizes, int n_in,
                              void* d_out, int out_size, void* d_ws, size_t ws_size,
                              hipStream_t stream) {
    const float* x     = (const float*)d_in[0];
    const int*   ei    = (const int*)d_in[1];      // [2, E] flattened int32
    const int*   src   = ei;                       // edge_index[0]
    const int*   dst   = ei + Ee;                  // edge_index[1]
    const int*   batch = (const int*)d_in[2];
    const int*   rt    = (const int*)d_in[3];

    const float* P[3][8];
    for (int l = 0; l < 3; ++l)
        for (int p = 0; p < 8; ++p)
            P[l][p] = (const float*)d_in[4 + l * 8 + p];
    const float* head_w = (const float*)d_in[28];
    const float* head_b = (const float*)d_in[29];

    // Workspace layout
    float* bufA      = (float*)d_ws;                     // N*H floats
    float* bufB      = bufA + (size_t)Nn * Hh;           // N*H floats
    int*   deg       = (int*)(bufB + (size_t)Nn * Hh);   // N ints
    int*   rowptr    = deg + Nn;                         // N+1 ints
    int*   cursor    = rowptr + Nn + 1;                  // N ints
    int*   partial   = cursor + Nn;                      // SCAN_NBLK ints
    int*   blockpref = partial + SCAN_NBLK;              // SCAN_NBLK ints
    int*   csr       = blockpref + SCAN_NBLK;            // E ints
    float* out       = (float*)d_out;

    const dim3 blk256(256), blk192(192);
    const int GRID_E = 1024;
    const int GRID_FC = (Nn + 63) / 64;   // 782 tiles

    // ----- Build CSR (dst -> srcs) -----
    hipMemsetAsync(deg, 0, Nn * sizeof(int), stream);
    count_deg_kernel<<<GRID_E, blk256, 0, stream>>>(dst, deg);
    block_sum_kernel<<<SCAN_NBLK, SCAN_BLK, 0, stream>>>(deg, partial);
    scan_partial_kernel<<<1, 256, 0, stream>>>(partial, blockpref);
    scan_apply_kernel<<<SCAN_NBLK, SCAN_BLK, 0, stream>>>(deg, blockpref, rowptr, cursor);
    scatter_csr_kernel<<<GRID_E, blk256, 0, stream>>>(src, dst, cursor, csr);

    // ----- Layer 1 (din = 32): agg(x) -> bufA, fc1 -> bufB, fc2 in place -----
    agg_csr_kernel<INF><<<1563, blk256, 0, stream>>>(x, rowptr, csr, bufA);
    fc_kernel<INF, true><<<GRID_FC, blk256, 0, stream>>>(bufA,
        P[0][0], P[0][1], P[0][2], P[0][3], P[0][4], P[0][5], bufB);
    fc_kernel<Hh, false><<<GRID_FC, blk256, 0, stream>>>(bufB,
        P[0][6], P[0][7], nullptr, nullptr, nullptr, nullptr, bufB);

    // ----- Layer 2 (din = 96): agg(bufB) -> bufA, fc1/fc2 in place -----
    agg_csr_kernel<Hh><<<6250, blk192, 0, stream>>>(bufB, rowptr, csr, bufA);
    fc_kernel<Hh, true><<<GRID_FC, blk256, 0, stream>>>(bufA,
        P[1][0], P[1][1], P[1][2], P[1][3], P[1][4], P[1][5], bufA);
    fc_kernel<Hh, false><<<GRID_FC, blk256, 0, stream>>>(bufA,
        P[1][6], P[1][7], nullptr, nullptr, nullptr, nullptr, bufA);

    // ----- Layer 3 (din = 96): agg(bufA) -> bufB, fc1/fc2 in place -----
    agg_csr_kernel<Hh><<<6250, blk192, 0, stream>>>(bufA, rowptr, csr, bufB);
    fc_kernel<Hh, true><<<GRID_FC, blk256, 0, stream>>>(bufB,
        P[2][0], P[2][1], P[2][2], P[2][3], P[2][4], P[2][5], bufB);
    fc_kernel<Hh, false><<<GRID_FC, blk256, 0, stream>>>(bufB,
        P[2][6], P[2][7], nullptr, nullptr, nullptr, nullptr, bufB);

    // ----- Fused pool + head -----
    pool_head_kernel<<<Bb, Hh, 0, stream>>>(bufB, batch, rt, head_w, head_b, out);
}

// Round 5
// 377.389 us; speedup vs baseline: 2.7755x; 1.1103x over previous
//
#include <hip/hip_runtime.h>

// Problem constants (from reference)
constexpr int Nn  = 50000;   // nodes
constexpr int Ee  = 800000;  // edges
constexpr int Bb  = 256;     // graphs
constexpr int INF = 32;      // input feature dim
constexpr int Hh  = 96;      // hidden dim
constexpr float BN_EPS = 1e-5f;

constexpr int SCAN_BLK  = 256;
constexpr int SCAN_NBLK = (Nn + SCAN_BLK - 1) / SCAN_BLK;   // 196

// ---------------------------------------------------------------------------
// CSR build: deg count -> hierarchical scan -> scatter
// ---------------------------------------------------------------------------
__global__ void count_deg_kernel(const int* __restrict__ dst, int* __restrict__ deg) {
    for (long e = (long)blockIdx.x * blockDim.x + threadIdx.x; e < Ee;
         e += (long)gridDim.x * blockDim.x)
        atomicAdd(&deg[dst[e]], 1);
}

__global__ void block_sum_kernel(const int* __restrict__ deg, int* __restrict__ partial) {
    const int t = threadIdx.x;
    const int idx = blockIdx.x * SCAN_BLK + t;
    int v = (idx < Nn) ? deg[idx] : 0;
    #pragma unroll
    for (int off = 32; off > 0; off >>= 1) v += __shfl_down(v, off, 64);
    __shared__ int ws[SCAN_BLK / 64];
    if ((t & 63) == 0) ws[t >> 6] = v;
    __syncthreads();
    if (t == 0) {
        int s = 0;
        #pragma unroll
        for (int w = 0; w < SCAN_BLK / 64; ++w) s += ws[w];
        partial[blockIdx.x] = s;
    }
}

__global__ void scan_partial_kernel(const int* __restrict__ partial, int* __restrict__ blockpref) {
    __shared__ int ps[256];
    const int t = threadIdx.x;
    ps[t] = (t < SCAN_NBLK) ? partial[t] : 0;
    __syncthreads();
    for (int d = 1; d < 256; d <<= 1) {
        int u = (t >= d) ? ps[t - d] : 0;
        __syncthreads();
        if (t >= d) ps[t] += u;
        __syncthreads();
    }
    if (t < SCAN_NBLK) blockpref[t] = (t == 0) ? 0 : ps[t - 1];
}

__global__ void scan_apply_kernel(const int* __restrict__ deg, const int* __restrict__ blockpref,
                                  int* __restrict__ rowptr, int* __restrict__ cursor) {
    __shared__ int ps[SCAN_BLK];
    const int t = threadIdx.x;
    const int idx = blockIdx.x * SCAN_BLK + t;
    const int v = (idx < Nn) ? deg[idx] : 0;
    ps[t] = v;
    __syncthreads();
    for (int d = 1; d < SCAN_BLK; d <<= 1) {
        int u = (t >= d) ? ps[t - d] : 0;
        __syncthreads();
        if (t >= d) ps[t] += u;
        __syncthreads();
    }
    if (idx < Nn) {
        int r = blockpref[blockIdx.x] + ps[t] - v;   // exclusive
        rowptr[idx] = r;
        cursor[idx] = r;
    }
    if (idx == Nn - 1) rowptr[Nn] = Ee;
}

__global__ void scatter_csr_kernel(const int* __restrict__ src, const int* __restrict__ dst,
                                   int* __restrict__ cursor, int* __restrict__ csr) {
    for (long e = (long)blockIdx.x * blockDim.x + threadIdx.x; e < Ee;
         e += (long)gridDim.x * blockDim.x) {
        int d = dst[e];
        int p = atomicAdd(&cursor[d], 1);
        csr[p] = src[e];
    }
}

// ---------------------------------------------------------------------------
// CSR aggregation with self term: out[i] = h[i] + sum_{j in N(i)} h[j]
// ---------------------------------------------------------------------------
template<int F>
__global__ void agg_csr_kernel(const float* __restrict__ h, const int* __restrict__ rowptr,
                               const int* __restrict__ csr, float* __restrict__ out) {
    constexpr int V = F / 4;                    // threads per node
    const int gpb = blockDim.x / V;             // node groups per block
    const int g = threadIdx.x / V;
    const int j = threadIdx.x % V;
    const float4* h4 = (const float4*)h;
    float4* out4 = (float4*)out;

    for (long node = (long)blockIdx.x * gpb + g; node < Nn; node += (long)gridDim.x * gpb) {
        const int e0 = rowptr[node];
        const int e1 = rowptr[node + 1];
        float4 acc = h4[node * V + j];          // self term
        for (int e = e0; e < e1; ++e) {
            const long s = csr[e];
            const float4 v = h4[s * V + j];
            acc.x += v.x; acc.y += v.y; acc.z += v.z; acc.w += v.w;
        }
        out4[node * V + j] = acc;
    }
}

// ---------------------------------------------------------------------------
// Register-blocked FC: out = relu(A[j] * (xin @ w)[n,j] + C[j])
// ---------------------------------------------------------------------------
template<int DIN, bool BN>
__global__ __launch_bounds__(256)
void fc_kernel(const float* __restrict__ xin, const float* __restrict__ w,
               const float* __restrict__ p0,      // BN ? b_in : b_out
               const float* __restrict__ gamma, const float* __restrict__ beta,
               const float* __restrict__ rmean, const float* __restrict__ rvar,
               float* __restrict__ out) {
    constexpr int XST = DIN + 4;
    constexpr int C4  = DIN / 4;
    __shared__ float ws[DIN * Hh];
    __shared__ float xs[64 * XST];

    const int tid = threadIdx.x;
    const int jt  = tid & 15;
    const int nt  = tid >> 4;
    const int j0  = jt * 6;
    const int nbase = blockIdx.x * 64;

    for (int i = tid * 4; i < DIN * Hh; i += 1024)
        *(float4*)&ws[i] = *(const float4*)&w[i];

    for (int idx = tid; idx < 64 * C4; idx += 256) {
        const int r = idx / C4, c4 = idx % C4;
        const int gr = nbase + r;
        float4 v = make_float4(0.f, 0.f, 0.f, 0.f);
        if (gr < Nn) v = *(const float4*)&xin[(long)gr * DIN + c4 * 4];
        *(float4*)&xs[r * XST + c4 * 4] = v;
    }

    float A[6], C[6];
    #pragma unroll
    for (int ji = 0; ji < 6; ++ji) {
        const int j = j0 + ji;
        if (BN) {
            const float s = gamma[j] * rsqrtf(rvar[j] + BN_EPS);
            A[ji] = s;
            C[ji] = (p0[j] - rmean[j]) * s + beta[j];
        } else {
            A[ji] = 1.0f;
            C[ji] = p0[j];
        }
    }
    __syncthreads();

    float acc[4][6] = {};
    #pragma unroll 4
    for (int k = 0; k < DIN; ++k) {
        float xv[4];
        #pragma unroll
        for (int ni = 0; ni < 4; ++ni) xv[ni] = xs[(nt * 4 + ni) * XST + k];
        float wv[6];
        #pragma unroll
        for (int q = 0; q < 3; ++q) {
            const float2 t = *(const float2*)&ws[k * Hh + j0 + 2 * q];
            wv[2 * q] = t.x; wv[2 * q + 1] = t.y;
        }
        #pragma unroll
        for (int ni = 0; ni < 4; ++ni)
            #pragma unroll
            for (int ji = 0; ji < 6; ++ji)
                acc[ni][ji] = fmaf(xv[ni], wv[ji], acc[ni][ji]);
    }

    #pragma unroll
    for (int ni = 0; ni < 4; ++ni) {
        const int node = nbase + nt * 4 + ni;
        if (node < Nn) {
            float* op = out + (long)node * Hh + j0;
            #pragma unroll
            for (int q = 0; q < 3; ++q) {
                float2 st;
                st.x = fmaxf(fmaf(acc[ni][2 * q],     A[2 * q],     C[2 * q]),     0.0f);
                st.y = fmaxf(fmaf(acc[ni][2 * q + 1], A[2 * q + 1], C[2 * q + 1]), 0.0f);
                *(float2*)&op[2 * q] = st;
            }
        }
    }
}

// ---------------------------------------------------------------------------
// Chunked pooling: each block owns 64 contiguous nodes; batch is sorted, so
// it flushes a register accumulator into pooled[b][j] only at graph
// boundaries (few atomics; pooled is tiny and L2-resident).
// ---------------------------------------------------------------------------
constexpr int PCHUNK = 64;
__global__ void pool_kernel(const float* __restrict__ h, const int* __restrict__ batch,
                            float* __restrict__ pooled) {
    const int j = threadIdx.x;                 // 0..95
    const int c0 = blockIdx.x * PCHUNK;
    const int c1 = min(c0 + PCHUNK, Nn);
    if (c0 >= Nn) return;

    int bcur = batch[c0];
    float acc = 0.0f;
    for (int n = c0; n < c1; ++n) {
        const int bb = batch[n];               // uniform across the block
        if (bb != bcur) {
            atomicAdd(&pooled[(long)bcur * Hh + j], acc);
            acc = 0.0f;
            bcur = bb;
        }
        acc += h[(long)n * Hh + j];
    }
    atomicAdd(&pooled[(long)bcur * Hh + j], acc);
}

// ---------------------------------------------------------------------------
// Head: out[b] = dot(pooled[b], head_w[rt[b]]) + head_b[rt[b]]
// ---------------------------------------------------------------------------
__global__ void head_kernel(const float* __restrict__ pooled, const int* __restrict__ rt,
                            const float* __restrict__ hw, const float* __restrict__ hb,
                            float* __restrict__ outv) {
    const int b = blockIdx.x;
    const int lane = threadIdx.x;
    const int t = rt[b];
    const float* pp = pooled + (long)b * Hh;
    const float* wp = hw + (long)t * Hh;
    float s = 0.0f;
    for (int j = lane; j < Hh; j += 64) s += pp[j] * wp[j];
    #pragma unroll
    for (int off = 32; off > 0; off >>= 1) s += __shfl_down(s, off, 64);
    if (lane == 0) outv[b] = s + hb[t];
}

// ---------------------------------------------------------------------------
extern "C" void kernel_launch(void* const* d_in, const int* in_sizes, int n_in,
                              void* d_out, int out_size, void* d_ws, size_t ws_size,
                              hipStream_t stream) {
    const float* x     = (const float*)d_in[0];
    const int*   ei    = (const int*)d_in[1];      // [2, E] flattened int32
    const int*   src   = ei;                       // edge_index[0]
    const int*   dst   = ei + Ee;                  // edge_index[1]
    const int*   batch = (const int*)d_in[2];
    const int*   rt    = (const int*)d_in[3];

    const float* P[3][8];
    for (int l = 0; l < 3; ++l)
        for (int p = 0; p < 8; ++p)
            P[l][p] = (const float*)d_in[4 + l * 8 + p];
    const float* head_w = (const float*)d_in[28];
    const float* head_b = (const float*)d_in[29];

    // Workspace layout
    float* bufA      = (float*)d_ws;                     // N*H floats
    float* bufB      = bufA + (size_t)Nn * Hh;           // N*H floats
    float* pooled    = bufB + (size_t)Nn * Hh;           // B*H floats
    int*   deg       = (int*)(pooled + (size_t)Bb * Hh); // N ints
    int*   rowptr    = deg + Nn;                         // N+1 ints
    int*   cursor    = rowptr + Nn + 1;                  // N ints
    int*   partial   = cursor + Nn;                      // SCAN_NBLK ints
    int*   blockpref = partial + SCAN_NBLK;              // SCAN_NBLK ints
    int*   csr       = blockpref + SCAN_NBLK;            // E ints
    float* out       = (float*)d_out;

    const dim3 blk256(256), blk192(192);
    const int GRID_E = 1024;
    const int GRID_FC = (Nn + 63) / 64;        // 782 tiles
    const int GRID_POOL = (Nn + PCHUNK - 1) / PCHUNK;

    // ----- Build CSR (dst -> srcs) -----
    hipMemsetAsync(deg, 0, Nn * sizeof(int), stream);
    count_deg_kernel<<<GRID_E, blk256, 0, stream>>>(dst, deg);
    block_sum_kernel<<<SCAN_NBLK, SCAN_BLK, 0, stream>>>(deg, partial);
    scan_partial_kernel<<<1, 256, 0, stream>>>(partial, blockpref);
    scan_apply_kernel<<<SCAN_NBLK, SCAN_BLK, 0, stream>>>(deg, blockpref, rowptr, cursor);
    scatter_csr_kernel<<<GRID_E, blk256, 0, stream>>>(src, dst, cursor, csr);

    // ----- Layer 1 (din = 32): agg(x) -> bufA, fc1 -> bufB, fc2 in place -----
    agg_csr_kernel<INF><<<1563, blk256, 0, stream>>>(x, rowptr, csr, bufA);
    fc_kernel<INF, true><<<GRID_FC, blk256, 0, stream>>>(bufA,
        P[0][0], P[0][1], P[0][2], P[0][3], P[0][4], P[0][5], bufB);
    fc_kernel<Hh, false><<<GRID_FC, blk256, 0, stream>>>(bufB,
        P[0][6], P[0][7], nullptr, nullptr, nullptr, nullptr, bufB);

    // ----- Layer 2 (din = 96): agg(bufB) -> bufA, fc1/fc2 in place -----
    agg_csr_kernel<Hh><<<6250, blk192, 0, stream>>>(bufB, rowptr, csr, bufA);
    fc_kernel<Hh, true><<<GRID_FC, blk256, 0, stream>>>(bufA,
        P[1][0], P[1][1], P[1][2], P[1][3], P[1][4], P[1][5], bufA);
    fc_kernel<Hh, false><<<GRID_FC, blk256, 0, stream>>>(bufA,
        P[1][6], P[1][7], nullptr, nullptr, nullptr, nullptr, bufA);

    // ----- Layer 3 (din = 96): agg(bufA) -> bufB, fc1/fc2 in place -----
    agg_csr_kernel<Hh><<<6250, blk192, 0, stream>>>(bufA, rowptr, csr, bufB);
    fc_kernel<Hh, true><<<GRID_FC, blk256, 0, stream>>>(bufB,
        P[2][0], P[2][1], P[2][2], P[2][3], P[2][4], P[2][5], bufB);
    fc_kernel<Hh, false><<<GRID_FC, blk256, 0, stream>>>(bufB,
        P[2][6], P[2][7], nullptr, nullptr, nullptr, nullptr, bufB);

    // ----- Pool (chunked, few atomics) + head -----
    hipMemsetAsync(pooled, 0, (size_t)Bb * Hh * sizeof(float), stream);
    pool_kernel<<<GRID_POOL, Hh, 0, stream>>>(bufB, batch, pooled);
    head_kernel<<<Bb, 64, 0, stream>>>(pooled, rt, head_w, head_b, out);
}

// Round 6
// 334.758 us; speedup vs baseline: 3.1289x; 1.1273x over previous
//
#include <hip/hip_runtime.h>

using u16 = unsigned short;
using u32 = unsigned int;

// Problem constants (from reference)
constexpr int Nn  = 50000;   // nodes
constexpr int Ee  = 800000;  // edges
constexpr int Bb  = 256;     // graphs
constexpr int INF = 32;      // input feature dim
constexpr int Hh  = 96;      // hidden dim
constexpr float BN_EPS = 1e-5f;

constexpr int SCAN_BLK  = 256;
constexpr int SCAN_NBLK = (Nn + SCAN_BLK - 1) / SCAN_BLK;   // 196

// ---------------- bf16 helpers (rne) ----------------
__device__ __forceinline__ float bfL(u32 u) { return __uint_as_float(u << 16); }
__device__ __forceinline__ float bfH(u32 u) { return __uint_as_float(u & 0xFFFF0000u); }
__device__ __forceinline__ u32 f2bfb(float f) {            // rounded bf16 bits (low 16)
    u32 b = __float_as_uint(f);
    return (b + 0x7FFFu + ((b >> 16) & 1u)) >> 16;
}
__device__ __forceinline__ float bf2f(u16 u) { return __uint_as_float(((u32)u) << 16); }

// ---------------------------------------------------------------------------
// CSR build: deg count -> hierarchical scan -> scatter (ushort payload)
// ---------------------------------------------------------------------------
__global__ void count_deg_kernel(const int* __restrict__ dst, int* __restrict__ deg) {
    for (long e = (long)blockIdx.x * blockDim.x + threadIdx.x; e < Ee;
         e += (long)gridDim.x * blockDim.x)
        atomicAdd(&deg[dst[e]], 1);
}

__global__ void block_sum_kernel(const int* __restrict__ deg, int* __restrict__ partial) {
    const int t = threadIdx.x;
    const int idx = blockIdx.x * SCAN_BLK + t;
    int v = (idx < Nn) ? deg[idx] : 0;
    #pragma unroll
    for (int off = 32; off > 0; off >>= 1) v += __shfl_down(v, off, 64);
    __shared__ int ws[SCAN_BLK / 64];
    if ((t & 63) == 0) ws[t >> 6] = v;
    __syncthreads();
    if (t == 0) {
        int s = 0;
        #pragma unroll
        for (int w = 0; w < SCAN_BLK / 64; ++w) s += ws[w];
        partial[blockIdx.x] = s;
    }
}

__global__ void scan_partial_kernel(const int* __restrict__ partial, int* __restrict__ blockpref) {
    __shared__ int ps[256];
    const int t = threadIdx.x;
    ps[t] = (t < SCAN_NBLK) ? partial[t] : 0;
    __syncthreads();
    for (int d = 1; d < 256; d <<= 1) {
        int u = (t >= d) ? ps[t - d] : 0;
        __syncthreads();
        if (t >= d) ps[t] += u;
        __syncthreads();
    }
    if (t < SCAN_NBLK) blockpref[t] = (t == 0) ? 0 : ps[t - 1];
}

__global__ void scan_apply_kernel(const int* __restrict__ deg, const int* __restrict__ blockpref,
                                  int* __restrict__ rowptr, int* __restrict__ cursor) {
    __shared__ int ps[SCAN_BLK];
    const int t = threadIdx.x;
    const int idx = blockIdx.x * SCAN_BLK + t;
    const int v = (idx < Nn) ? deg[idx] : 0;
    ps[t] = v;
    __syncthreads();
    for (int d = 1; d < SCAN_BLK; d <<= 1) {
        int u = (t >= d) ? ps[t - d] : 0;
        __syncthreads();
        if (t >= d) ps[t] += u;
        __syncthreads();
    }
    if (idx < Nn) {
        int r = blockpref[blockIdx.x] + ps[t] - v;   // exclusive
        rowptr[idx] = r;
        cursor[idx] = r;
    }
    if (idx == Nn - 1) rowptr[Nn] = Ee;
}

__global__ void scatter_csr_kernel(const int* __restrict__ src, const int* __restrict__ dst,
                                   int* __restrict__ cursor, u16* __restrict__ csr) {
    for (long e = (long)blockIdx.x * blockDim.x + threadIdx.x; e < Ee;
         e += (long)gridDim.x * blockDim.x) {
        int d = dst[e];
        int p = atomicAdd(&cursor[d], 1);
        csr[p] = (u16)src[e];
    }
}

// ---------------------------------------------------------------------------
// Layer-1 aggregation (fp32, F=32): out[i] = x[i] + sum_j x[j]
// ---------------------------------------------------------------------------
__global__ void agg_csr_f32_kernel(const float* __restrict__ h, const int* __restrict__ rowptr,
                                   const u16* __restrict__ csr, float* __restrict__ out) {
    constexpr int V = INF / 4;                  // 8 threads per node
    const int gpb = blockDim.x / V;             // 32 groups per 256-block
    const int g = threadIdx.x / V;
    const int j = threadIdx.x % V;
    const float4* h4 = (const float4*)h;
    float4* out4 = (float4*)out;

    const long node = (long)blockIdx.x * gpb + g;
    if (node >= Nn) return;
    const int e0 = rowptr[node];
    const int e1 = rowptr[node + 1];
    float4 acc = h4[node * V + j];              // self term
    for (int e = e0; e < e1; ++e) {
        const long s = csr[e];
        const float4 v = h4[s * V + j];
        acc.x += v.x; acc.y += v.y; acc.z += v.z; acc.w += v.w;
    }
    out4[node * V + j] = acc;
}

// ---------------------------------------------------------------------------
// 96-wide aggregation on bf16 tables: out[i] = h[i] + sum_j h[j]  (fp32 accum)
// 12 threads per node, one uint4 (8 bf16) each. Block 192 = 16 nodes.
// ---------------------------------------------------------------------------
__global__ void agg_csr_bf16_kernel(const u16* __restrict__ h, const int* __restrict__ rowptr,
                                    const u16* __restrict__ csr, u16* __restrict__ out) {
    const int g = threadIdx.x / 12;             // 16 groups
    const int j = threadIdx.x % 12;
    const long node = (long)blockIdx.x * 16 + g;
    if (node >= Nn) return;

    const uint4* h4 = (const uint4*)h;          // row = 12 uint4
    const int e0 = rowptr[node];
    const int e1 = rowptr[node + 1];

    uint4 U = h4[node * 12 + j];
    float a0 = bfL(U.x), a1 = bfH(U.x), a2 = bfL(U.y), a3 = bfH(U.y);
    float a4 = bfL(U.z), a5 = bfH(U.z), a6 = bfL(U.w), a7 = bfH(U.w);

    for (int e = e0; e < e1; ++e) {
        const long s = csr[e];
        const uint4 V = h4[s * 12 + j];
        a0 += bfL(V.x); a1 += bfH(V.x); a2 += bfL(V.y); a3 += bfH(V.y);
        a4 += bfL(V.z); a5 += bfH(V.z); a6 += bfL(V.w); a7 += bfH(V.w);
    }

    uint4 R;
    R.x = f2bfb(a0) | (f2bfb(a1) << 16);
    R.y = f2bfb(a2) | (f2bfb(a3) << 16);
    R.z = f2bfb(a4) | (f2bfb(a5) << 16);
    R.w = f2bfb(a6) | (f2bfb(a7) << 16);
    ((uint4*)out)[node * 12 + j] = R;
}

// ---------------------------------------------------------------------------
// Register-blocked FC: out = relu(A[j] * (xin @ w)[n,j] + C[j])
//   BN: A = gamma*rsqrt(var+eps), C = (b_in - rmean)*A + beta; else A=1,C=b.
//   BIN: input table bf16 (u16), else fp32. BOUT: output bf16, else fp32.
// Block 256 -> 64-node x 96-feat tile, thread = 4 nodes x 6 feats.
// In-place safe (tile fully staged to LDS before writes).
// ---------------------------------------------------------------------------
template<int DIN, bool BN, bool BIN, bool BOUT>
__global__ __launch_bounds__(256)
void fc_kernel(const void* __restrict__ xin_, const float* __restrict__ w,
               const float* __restrict__ p0,
               const float* __restrict__ gamma, const float* __restrict__ beta,
               const float* __restrict__ rmean, const float* __restrict__ rvar,
               void* __restrict__ out_) {
    constexpr int XST = DIN + 4;
    __shared__ float ws[DIN * Hh];
    __shared__ float xs[64 * XST];

    const int tid = threadIdx.x;
    const int jt  = tid & 15;
    const int nt  = tid >> 4;
    const int j0  = jt * 6;
    const int nbase = blockIdx.x * 64;

    for (int i = tid * 4; i < DIN * Hh; i += 1024)
        *(float4*)&ws[i] = *(const float4*)&w[i];

    if constexpr (BIN) {
        const u16* xi = (const u16*)xin_;
        for (int idx = tid; idx < 64 * (DIN / 8); idx += 256) {
            const int r = idx / (DIN / 8), c = idx % (DIN / 8);
            const int gr = nbase + r;
            uint4 U = make_uint4(0u, 0u, 0u, 0u);
            if (gr < Nn) U = ((const uint4*)(xi + (long)gr * DIN))[c];
            float* xp = &xs[r * XST + c * 8];
            xp[0] = bfL(U.x); xp[1] = bfH(U.x); xp[2] = bfL(U.y); xp[3] = bfH(U.y);
            xp[4] = bfL(U.z); xp[5] = bfH(U.z); xp[6] = bfL(U.w); xp[7] = bfH(U.w);
        }
    } else {
        const float* xi = (const float*)xin_;
        for (int idx = tid; idx < 64 * (DIN / 4); idx += 256) {
            const int r = idx / (DIN / 4), c4 = idx % (DIN / 4);
            const int gr = nbase + r;
            float4 v = make_float4(0.f, 0.f, 0.f, 0.f);
            if (gr < Nn) v = *(const float4*)&xi[(long)gr * DIN + c4 * 4];
            *(float4*)&xs[r * XST + c4 * 4] = v;
        }
    }

    float A[6], C[6];
    #pragma unroll
    for (int ji = 0; ji < 6; ++ji) {
        const int j = j0 + ji;
        if (BN) {
            const float s = gamma[j] * rsqrtf(rvar[j] + BN_EPS);
            A[ji] = s;
            C[ji] = (p0[j] - rmean[j]) * s + beta[j];
        } else {
            A[ji] = 1.0f;
            C[ji] = p0[j];
        }
    }
    __syncthreads();

    float acc[4][6] = {};
    #pragma unroll 4
    for (int k = 0; k < DIN; ++k) {
        float xv[4];
        #pragma unroll
        for (int ni = 0; ni < 4; ++ni) xv[ni] = xs[(nt * 4 + ni) * XST + k];
        float wv[6];
        #pragma unroll
        for (int q = 0; q < 3; ++q) {
            const float2 t = *(const float2*)&ws[k * Hh + j0 + 2 * q];
            wv[2 * q] = t.x; wv[2 * q + 1] = t.y;
        }
        #pragma unroll
        for (int ni = 0; ni < 4; ++ni)
            #pragma unroll
            for (int ji = 0; ji < 6; ++ji)
                acc[ni][ji] = fmaf(xv[ni], wv[ji], acc[ni][ji]);
    }

    #pragma unroll
    for (int ni = 0; ni < 4; ++ni) {
        const int node = nbase + nt * 4 + ni;
        if (node < Nn) {
            #pragma unroll
            for (int q = 0; q < 3; ++q) {
                const float r0 = fmaxf(fmaf(acc[ni][2 * q],     A[2 * q],     C[2 * q]),     0.0f);
                const float r1 = fmaxf(fmaf(acc[ni][2 * q + 1], A[2 * q + 1], C[2 * q + 1]), 0.0f);
                if constexpr (BOUT) {
                    u16* op = (u16*)out_ + (long)node * Hh + j0;
                    *(u32*)(op + 2 * q) = f2bfb(r0) | (f2bfb(r1) << 16);
                } else {
                    float* op = (float*)out_ + (long)node * Hh + j0;
                    float2 st; st.x = r0; st.y = r1;
                    *(float2*)&op[2 * q] = st;
                }
            }
        }
    }
}

// ---------------------------------------------------------------------------
// Chunked pooling over bf16 table (batch sorted; boundary-flush atomics)
// ---------------------------------------------------------------------------
constexpr int PCHUNK = 64;
__global__ void pool_kernel(const u16* __restrict__ h, const int* __restrict__ batch,
                            float* __restrict__ pooled) {
    const int j = threadIdx.x;                 // 0..95
    const int c0 = blockIdx.x * PCHUNK;
    const int c1 = min(c0 + PCHUNK, Nn);
    if (c0 >= Nn) return;

    int bcur = batch[c0];
    float acc = 0.0f;
    for (int n = c0; n < c1; ++n) {
        const int bb = batch[n];
        if (bb != bcur) {
            atomicAdd(&pooled[(long)bcur * Hh + j], acc);
            acc = 0.0f;
            bcur = bb;
        }
        acc += bf2f(h[(long)n * Hh + j]);
    }
    atomicAdd(&pooled[(long)bcur * Hh + j], acc);
}

// ---------------------------------------------------------------------------
// Head: out[b] = dot(pooled[b], head_w[rt[b]]) + head_b[rt[b]]
// ---------------------------------------------------------------------------
__global__ void head_kernel(const float* __restrict__ pooled, const int* __restrict__ rt,
                            const float* __restrict__ hw, const float* __restrict__ hb,
                            float* __restrict__ outv) {
    const int b = blockIdx.x;
    const int lane = threadIdx.x;
    const int t = rt[b];
    const float* pp = pooled + (long)b * Hh;
    const float* wp = hw + (long)t * Hh;
    float s = 0.0f;
    for (int j = lane; j < Hh; j += 64) s += pp[j] * wp[j];
    #pragma unroll
    for (int off = 32; off > 0; off >>= 1) s += __shfl_down(s, off, 64);
    if (lane == 0) outv[b] = s + hb[t];
}

// ---------------------------------------------------------------------------
extern "C" void kernel_launch(void* const* d_in, const int* in_sizes, int n_in,
                              void* d_out, int out_size, void* d_ws, size_t ws_size,
                              hipStream_t stream) {
    const float* x     = (const float*)d_in[0];
    const int*   ei    = (const int*)d_in[1];      // [2, E] flattened int32
    const int*   src   = ei;
    const int*   dst   = ei + Ee;
    const int*   batch = (const int*)d_in[2];
    const int*   rt    = (const int*)d_in[3];

    const float* P[3][8];
    for (int l = 0; l < 3; ++l)
        for (int p = 0; p < 8; ++p)
            P[l][p] = (const float*)d_in[4 + l * 8 + p];
    const float* head_w = (const float*)d_in[28];
    const float* head_b = (const float*)d_in[29];

    // Workspace layout
    u16*   tA        = (u16*)d_ws;                       // N*H bf16
    u16*   tB        = tA + (size_t)Nn * Hh;             // N*H bf16
    u16*   tG        = tB + (size_t)Nn * Hh;             // N*H bf16 (scratch)
    float* aggF      = (float*)(tG + (size_t)Nn * Hh);   // N*INF fp32
    float* pooled    = aggF + (size_t)Nn * INF;          // B*H fp32
    int*   deg       = (int*)(pooled + (size_t)Bb * Hh); // N ints
    int*   rowptr    = deg + Nn;                         // N+1 ints
    int*   cursor    = rowptr + Nn + 1;                  // N ints
    int*   partial   = cursor + Nn;                      // SCAN_NBLK ints
    int*   blockpref = partial + SCAN_NBLK;              // SCAN_NBLK ints
    u16*   csr       = (u16*)(blockpref + SCAN_NBLK);    // E u16
    float* out       = (float*)d_out;

    const dim3 blk256(256), blk192(192);
    const int GRID_E = 1024;
    const int GRID_FC = (Nn + 63) / 64;                  // 782 tiles
    const int GRID_AGG32 = (Nn + 31) / 32;               // 1563
    const int GRID_AGG96 = (Nn + 15) / 16;               // 3125
    const int GRID_POOL  = (Nn + PCHUNK - 1) / PCHUNK;

    // ----- Build CSR (dst -> srcs), u16 payload -----
    hipMemsetAsync(deg, 0, Nn * sizeof(int), stream);
    count_deg_kernel<<<GRID_E, blk256, 0, stream>>>(dst, deg);
    block_sum_kernel<<<SCAN_NBLK, SCAN_BLK, 0, stream>>>(deg, partial);
    scan_partial_kernel<<<1, 256, 0, stream>>>(partial, blockpref);
    scan_apply_kernel<<<SCAN_NBLK, SCAN_BLK, 0, stream>>>(deg, blockpref, rowptr, cursor);
    scatter_csr_kernel<<<GRID_E, blk256, 0, stream>>>(src, dst, cursor, csr);

    // ----- Layer 1: agg32(x)->aggF ; fc1(aggF)->tG ; fc2(tG)->tA -----
    agg_csr_f32_kernel<<<GRID_AGG32, blk256, 0, stream>>>(x, rowptr, csr, aggF);
    fc_kernel<INF, true, false, true><<<GRID_FC, blk256, 0, stream>>>(aggF,
        P[0][0], P[0][1], P[0][2], P[0][3], P[0][4], P[0][5], tG);
    fc_kernel<Hh, false, true, true><<<GRID_FC, blk256, 0, stream>>>(tG,
        P[0][6], P[0][7], nullptr, nullptr, nullptr, nullptr, tA);

    // ----- Layer 2: agg96(tA)->tG ; fc1 in-place tG ; fc2(tG)->tB -----
    agg_csr_bf16_kernel<<<GRID_AGG96, blk192, 0, stream>>>(tA, rowptr, csr, tG);
    fc_kernel<Hh, true, true, true><<<GRID_FC, blk256, 0, stream>>>(tG,
        P[1][0], P[1][1], P[1][2], P[1][3], P[1][4], P[1][5], tG);
    fc_kernel<Hh, false, true, true><<<GRID_FC, blk256, 0, stream>>>(tG,
        P[1][6], P[1][7], nullptr, nullptr, nullptr, nullptr, tB);

    // ----- Layer 3: agg96(tB)->tG ; fc1 in-place tG ; fc2(tG)->tA -----
    agg_csr_bf16_kernel<<<GRID_AGG96, blk192, 0, stream>>>(tB, rowptr, csr, tG);
    fc_kernel<Hh, true, true, true><<<GRID_FC, blk256, 0, stream>>>(tG,
        P[2][0], P[2][1], P[2][2], P[2][3], P[2][4], P[2][5], tG);
    fc_kernel<Hh, false, true, true><<<GRID_FC, blk256, 0, stream>>>(tG,
        P[2][6], P[2][7], nullptr, nullptr, nullptr, nullptr, tA);

    // ----- Pool (chunked) + head -----
    hipMemsetAsync(pooled, 0, (size_t)Bb * Hh * sizeof(float), stream);
    pool_kernel<<<GRID_POOL, Hh, 0, stream>>>(tA, batch, pooled);
    head_kernel<<<Bb, 64, 0, stream>>>(pooled, rt, head_w, head_b, out);
}

// Round 7
// 299.458 us; speedup vs baseline: 3.4977x; 1.1179x over previous
//
#include <hip/hip_runtime.h>

using u16 = unsigned short;
using u32 = unsigned int;

// Problem constants (from reference)
constexpr int Nn  = 50000;   // nodes
constexpr int Ee  = 800000;  // edges
constexpr int Bb  = 256;     // graphs
constexpr int INF = 32;      // input feature dim
constexpr int Hh  = 96;      // hidden dim
constexpr float BN_EPS = 1e-5f;

// Binned CSR build parameters
constexpr int BINW = 256;                      // nodes per bin
constexpr int NBIN = (Nn + BINW - 1) / BINW;   // 196
constexpr int P1B  = 256;                      // pass-1 blocks
constexpr int EPB  = Ee / P1B;                 // 3125 edges per block (exact)
constexpr int CAP  = 64;                       // per (block,bin) capacity (mean 16, 12 sigma)

// ---------------- bf16 helpers (rne) ----------------
__device__ __forceinline__ float bfL(u32 u) { return __uint_as_float(u << 16); }
__device__ __forceinline__ float bfH(u32 u) { return __uint_as_float(u & 0xFFFF0000u); }
__device__ __forceinline__ u32 f2bfb(float f) {            // rounded bf16 bits (low 16)
    u32 b = __float_as_uint(f);
    return (b + 0x7FFFu + ((b >> 16) & 1u)) >> 16;
}
__device__ __forceinline__ float bf2f(u16 u) { return __uint_as_float(((u32)u) << 16); }

// ---------------------------------------------------------------------------
// x -> bf16 table (N x 32)
// ---------------------------------------------------------------------------
__global__ void x2bf_kernel(const float* __restrict__ x, u16* __restrict__ xb) {
    const int total = Nn * INF / 8;
    for (int i = blockIdx.x * 256 + threadIdx.x; i < total; i += gridDim.x * 256) {
        const float4 a = ((const float4*)x)[2 * i];
        const float4 b = ((const float4*)x)[2 * i + 1];
        uint4 R;
        R.x = f2bfb(a.x) | (f2bfb(a.y) << 16);
        R.y = f2bfb(a.z) | (f2bfb(a.w) << 16);
        R.z = f2bfb(b.x) | (f2bfb(b.y) << 16);
        R.w = f2bfb(b.z) | (f2bfb(b.w) << 16);
        ((uint4*)xb)[i] = R;
    }
}

// ---------------------------------------------------------------------------
// CSR build pass 1: bin edges into per-(block,bin) private regions.
// LDS cursors only; every binbuf cache line is written by exactly one block.
// counts layout: [k * P1B + b] (coalesced for passes 2/3).
// ---------------------------------------------------------------------------
__global__ __launch_bounds__(256)
void p1_bin_kernel(const int* __restrict__ src, const int* __restrict__ dst,
                   u32* __restrict__ binbuf, int* __restrict__ counts) {
    __shared__ int cur[NBIN];
    const int b = blockIdx.x, tid = threadIdx.x;
    for (int k = tid; k < NBIN; k += 256) cur[k] = 0;
    __syncthreads();
    const long e0 = (long)b * EPB;
    for (int i = tid; i < EPB; i += 256) {
        const long e = e0 + i;
        const int d = dst[e];
        const int k = d >> 8;
        const int pos = atomicAdd(&cur[k], 1);
        binbuf[((long)b * NBIN + k) * CAP + pos] = ((u32)(d & 255) << 16) | (u32)src[e];
    }
    __syncthreads();
    for (int k = tid; k < NBIN; k += 256) counts[k * P1B + b] = cur[k];
}

// ---------------------------------------------------------------------------
// CSR build pass 2: bin totals -> exclusive prefix (binbase); rowptr[N] = E.
// ---------------------------------------------------------------------------
__global__ void p2_binscan_kernel(const int* __restrict__ counts, int* __restrict__ binbase,
                                  int* __restrict__ rowptr) {
    __shared__ int ps[256];
    const int t = threadIdx.x;
    int tot = 0;
    if (t < NBIN) {
        const int* cp = counts + t * P1B;
        for (int b = 0; b < P1B; ++b) tot += cp[b];
    }
    ps[t] = tot;
    __syncthreads();
    for (int d = 1; d < 256; d <<= 1) {
        int u = (t >= d) ? ps[t - d] : 0;
        __syncthreads();
        if (t >= d) ps[t] += u;
        __syncthreads();
    }
    if (t < NBIN) binbase[t] = ps[t] - tot;   // exclusive prefix
    if (t == 0) rowptr[Nn] = Ee;
}

// ---------------------------------------------------------------------------
// CSR build pass 3: one block per bin. LDS histogram of the bin's 256 nodes,
// write rowptr slice (coalesced), then scatter u16 srcs into the bin's
// contiguous CSR window (single-block-owned -> L2-local full lines).
// ---------------------------------------------------------------------------
__global__ __launch_bounds__(256)
void p3_binsort_kernel(const u32* __restrict__ binbuf, const int* __restrict__ counts,
                       const int* __restrict__ binbase, int* __restrict__ rowptr,
                       u16* __restrict__ csr) {
    __shared__ int cnt[P1B];
    __shared__ int lhist[BINW];
    __shared__ int lpref[BINW];
    const int k = blockIdx.x, tid = threadIdx.x;

    for (int b = tid; b < P1B; b += 256) cnt[b] = counts[k * P1B + b];
    lhist[tid] = 0;
    __syncthreads();

    // histogram of local dst (high 16 bits)
    for (int flat = tid; flat < P1B * CAP; flat += 256) {
        const int b = flat / CAP, i = flat % CAP;
        if (i < cnt[b])
            atomicAdd(&lhist[binbuf[((long)b * NBIN + k) * CAP + i] >> 16], 1);
    }
    __syncthreads();

    // exclusive scan of lhist -> lpref
    const int v = lhist[tid];
    lpref[tid] = v;
    __syncthreads();
    for (int d = 1; d < 256; d <<= 1) {
        int u = (tid >= d) ? lpref[tid - d] : 0;
        __syncthreads();
        if (tid >= d) lpref[tid] += u;
        __syncthreads();
    }
    lpref[tid] -= v;

    const int base = binbase[k];
    const int node = k * BINW + tid;
    if (node < Nn) rowptr[node] = base + lpref[tid];
    lhist[tid] = 0;                         // reuse as cursor
    __syncthreads();

    // scatter into the bin's CSR window
    for (int flat = tid; flat < P1B * CAP; flat += 256) {
        const int b = flat / CAP, i = flat % CAP;
        if (i < cnt[b]) {
            const u32 pv = binbuf[((long)b * NBIN + k) * CAP + i];
            const int dl = pv >> 16;
            const int pos = base + lpref[dl] + atomicAdd(&lhist[dl], 1);
            csr[pos] = (u16)(pv & 0xFFFFu);
        }
    }
}

// ---------------------------------------------------------------------------
// Layer-1 aggregation on bf16 x (F=32): out[i] = x[i] + sum_j x[j]  (fp32 out)
// 4 threads per node (uint4 = 8 bf16 each), block 256 = 64 nodes.
// ---------------------------------------------------------------------------
__global__ void agg32_bf16_kernel(const u16* __restrict__ xb, const int* __restrict__ rowptr,
                                  const u16* __restrict__ csr, float* __restrict__ out) {
    const int g = threadIdx.x >> 2;
    const int j = threadIdx.x & 3;
    const long node = (long)blockIdx.x * 64 + g;
    if (node >= Nn) return;

    const uint4* h4 = (const uint4*)xb;        // row = 4 uint4
    const int e0 = rowptr[node], e1 = rowptr[node + 1];

    uint4 U = h4[node * 4 + j];
    float a0 = bfL(U.x), a1 = bfH(U.x), a2 = bfL(U.y), a3 = bfH(U.y);
    float a4 = bfL(U.z), a5 = bfH(U.z), a6 = bfL(U.w), a7 = bfH(U.w);
    for (int e = e0; e < e1; ++e) {
        const long s = csr[e];
        const uint4 V = h4[s * 4 + j];
        a0 += bfL(V.x); a1 += bfH(V.x); a2 += bfL(V.y); a3 += bfH(V.y);
        a4 += bfL(V.z); a5 += bfH(V.z); a6 += bfL(V.w); a7 += bfH(V.w);
    }
    float* op = out + node * INF + j * 8;
    *(float4*)op       = make_float4(a0, a1, a2, a3);
    *(float4*)(op + 4) = make_float4(a4, a5, a6, a7);
}

// ---------------------------------------------------------------------------
// 96-wide aggregation on bf16 tables: out[i] = h[i] + sum_j h[j]  (fp32 accum)
// 12 threads per node, one uint4 (8 bf16) each. Block 192 = 16 nodes.
// ---------------------------------------------------------------------------
__global__ void agg_csr_bf16_kernel(const u16* __restrict__ h, const int* __restrict__ rowptr,
                                    const u16* __restrict__ csr, u16* __restrict__ out) {
    const int g = threadIdx.x / 12;
    const int j = threadIdx.x % 12;
    const long node = (long)blockIdx.x * 16 + g;
    if (node >= Nn) return;

    const uint4* h4 = (const uint4*)h;          // row = 12 uint4
    const int e0 = rowptr[node], e1 = rowptr[node + 1];

    uint4 U = h4[node * 12 + j];
    float a0 = bfL(U.x), a1 = bfH(U.x), a2 = bfL(U.y), a3 = bfH(U.y);
    float a4 = bfL(U.z), a5 = bfH(U.z), a6 = bfL(U.w), a7 = bfH(U.w);
    for (int e = e0; e < e1; ++e) {
        const long s = csr[e];
        const uint4 V = h4[s * 12 + j];
        a0 += bfL(V.x); a1 += bfH(V.x); a2 += bfL(V.y); a3 += bfH(V.y);
        a4 += bfL(V.z); a5 += bfH(V.z); a6 += bfL(V.w); a7 += bfH(V.w);
    }
    uint4 R;
    R.x = f2bfb(a0) | (f2bfb(a1) << 16);
    R.y = f2bfb(a2) | (f2bfb(a3) << 16);
    R.z = f2bfb(a4) | (f2bfb(a5) << 16);
    R.w = f2bfb(a6) | (f2bfb(a7) << 16);
    ((uint4*)out)[node * 12 + j] = R;
}

// ---------------------------------------------------------------------------
// Register-blocked FC: out = relu(A[j] * (xin @ w)[n,j] + C[j])
//   BN: A = gamma*rsqrt(var+eps), C = (b_in - rmean)*A + beta; else A=1,C=b.
//   BIN: input table bf16, else fp32. BOUT: output bf16, else fp32.
// Block 256 -> 64-node x 96-feat tile, thread = 4 nodes x 6 feats.
// In-place safe (tile fully staged to LDS before writes).
// ---------------------------------------------------------------------------
template<int DIN, bool BN, bool BIN, bool BOUT>
__global__ __launch_bounds__(256)
void fc_kernel(const void* __restrict__ xin_, const float* __restrict__ w,
               const float* __restrict__ p0,
               const float* __restrict__ gamma, const float* __restrict__ beta,
               const float* __restrict__ rmean, const float* __restrict__ rvar,
               void* __restrict__ out_) {
    constexpr int XST = DIN + 4;
    __shared__ float ws[DIN * Hh];
    __shared__ float xs[64 * XST];

    const int tid = threadIdx.x;
    const int jt  = tid & 15;
    const int nt  = tid >> 4;
    const int j0  = jt * 6;
    const int nbase = blockIdx.x * 64;

    for (int i = tid * 4; i < DIN * Hh; i += 1024)
        *(float4*)&ws[i] = *(const float4*)&w[i];

    if constexpr (BIN) {
        const u16* xi = (const u16*)xin_;
        for (int idx = tid; idx < 64 * (DIN / 8); idx += 256) {
            const int r = idx / (DIN / 8), c = idx % (DIN / 8);
            const int gr = nbase + r;
            uint4 U = make_uint4(0u, 0u, 0u, 0u);
            if (gr < Nn) U = ((const uint4*)(xi + (long)gr * DIN))[c];
            float* xp = &xs[r * XST + c * 8];
            xp[0] = bfL(U.x); xp[1] = bfH(U.x); xp[2] = bfL(U.y); xp[3] = bfH(U.y);
            xp[4] = bfL(U.z); xp[5] = bfH(U.z); xp[6] = bfL(U.w); xp[7] = bfH(U.w);
        }
    } else {
        const float* xi = (const float*)xin_;
        for (int idx = tid; idx < 64 * (DIN / 4); idx += 256) {
            const int r = idx / (DIN / 4), c4 = idx % (DIN / 4);
            const int gr = nbase + r;
            float4 v = make_float4(0.f, 0.f, 0.f, 0.f);
            if (gr < Nn) v = *(const float4*)&xi[(long)gr * DIN + c4 * 4];
            *(float4*)&xs[r * XST + c4 * 4] = v;
        }
    }

    float A[6], C[6];
    #pragma unroll
    for (int ji = 0; ji < 6; ++ji) {
        const int j = j0 + ji;
        if (BN) {
            const float s = gamma[j] * rsqrtf(rvar[j] + BN_EPS);
            A[ji] = s;
            C[ji] = (p0[j] - rmean[j]) * s + beta[j];
        } else {
            A[ji] = 1.0f;
            C[ji] = p0[j];
        }
    }
    __syncthreads();

    float acc[4][6] = {};
    #pragma unroll 4
    for (int k = 0; k < DIN; ++k) {
        float xv[4];
        #pragma unroll
        for (int ni = 0; ni < 4; ++ni) xv[ni] = xs[(nt * 4 + ni) * XST + k];
        float wv[6];
        #pragma unroll
        for (int q = 0; q < 3; ++q) {
            const float2 t = *(const float2*)&ws[k * Hh + j0 + 2 * q];
            wv[2 * q] = t.x; wv[2 * q + 1] = t.y;
        }
        #pragma unroll
        for (int ni = 0; ni < 4; ++ni)
            #pragma unroll
            for (int ji = 0; ji < 6; ++ji)
                acc[ni][ji] = fmaf(xv[ni], wv[ji], acc[ni][ji]);
    }

    #pragma unroll
    for (int ni = 0; ni < 4; ++ni) {
        const int node = nbase + nt * 4 + ni;
        if (node < Nn) {
            #pragma unroll
            for (int q = 0; q < 3; ++q) {
                const float r0 = fmaxf(fmaf(acc[ni][2 * q],     A[2 * q],     C[2 * q]),     0.0f);
                const float r1 = fmaxf(fmaf(acc[ni][2 * q + 1], A[2 * q + 1], C[2 * q + 1]), 0.0f);
                if constexpr (BOUT) {
                    u16* op = (u16*)out_ + (long)node * Hh + j0;
                    *(u32*)(op + 2 * q) = f2bfb(r0) | (f2bfb(r1) << 16);
                } else {
                    float* op = (float*)out_ + (long)node * Hh + j0;
                    float2 st; st.x = r0; st.y = r1;
                    *(float2*)&op[2 * q] = st;
                }
            }
        }
    }
}

// ---------------------------------------------------------------------------
// Chunked pooling over bf16 table (batch sorted; boundary-flush atomics)
// ---------------------------------------------------------------------------
constexpr int PCHUNK = 64;
__global__ void pool_kernel(const u16* __restrict__ h, const int* __restrict__ batch,
                            float* __restrict__ pooled) {
    const int j = threadIdx.x;                 // 0..95
    const int c0 = blockIdx.x * PCHUNK;
    const int c1 = min(c0 + PCHUNK, Nn);
    if (c0 >= Nn) return;

    int bcur = batch[c0];
    float acc = 0.0f;
    for (int n = c0; n < c1; ++n) {
        const int bb = batch[n];
        if (bb != bcur) {
            atomicAdd(&pooled[(long)bcur * Hh + j], acc);
            acc = 0.0f;
            bcur = bb;
        }
        acc += bf2f(h[(long)n * Hh + j]);
    }
    atomicAdd(&pooled[(long)bcur * Hh + j], acc);
}

// ---------------------------------------------------------------------------
// Head: out[b] = dot(pooled[b], head_w[rt[b]]) + head_b[rt[b]]
// ---------------------------------------------------------------------------
__global__ void head_kernel(const float* __restrict__ pooled, const int* __restrict__ rt,
                            const float* __restrict__ hw, const float* __restrict__ hb,
                            float* __restrict__ outv) {
    const int b = blockIdx.x;
    const int lane = threadIdx.x;
    const int t = rt[b];
    const float* pp = pooled + (long)b * Hh;
    const float* wp = hw + (long)t * Hh;
    float s = 0.0f;
    for (int j = lane; j < Hh; j += 64) s += pp[j] * wp[j];
    #pragma unroll
    for (int off = 32; off > 0; off >>= 1) s += __shfl_down(s, off, 64);
    if (lane == 0) outv[b] = s + hb[t];
}

// ---------------------------------------------------------------------------
extern "C" void kernel_launch(void* const* d_in, const int* in_sizes, int n_in,
                              void* d_out, int out_size, void* d_ws, size_t ws_size,
                              hipStream_t stream) {
    const float* x     = (const float*)d_in[0];
    const int*   ei    = (const int*)d_in[1];      // [2, E] flattened int32
    const int*   src   = ei;
    const int*   dst   = ei + Ee;
    const int*   batch = (const int*)d_in[2];
    const int*   rt    = (const int*)d_in[3];

    const float* P[3][8];
    for (int l = 0; l < 3; ++l)
        for (int p = 0; p < 8; ++p)
            P[l][p] = (const float*)d_in[4 + l * 8 + p];
    const float* head_w = (const float*)d_in[28];
    const float* head_b = (const float*)d_in[29];

    // Workspace layout
    const size_t NH = (size_t)Nn * Hh;
    u16*   tA      = (u16*)d_ws;                     // N*H bf16
    u16*   tB      = tA + NH;                        // N*H bf16
    u16*   tG      = tB + NH;                        // N*H bf16 (scratch)
    float* aggF    = (float*)(tG + NH);              // N*INF fp32
    u16*   xb      = (u16*)(aggF + (size_t)Nn * INF);// N*INF bf16
    float* pooled  = (float*)(xb + (size_t)Nn * INF);// B*H fp32
    int*   rowptr  = (int*)(pooled + (size_t)Bb * Hh); // N+1 ints
    int*   counts  = rowptr + Nn + 1;                // NBIN*P1B ints
    int*   binbase = counts + NBIN * P1B;            // NBIN ints
    u16*   csr     = (u16*)(binbase + NBIN);         // E u16
    // binbuf overlays tG + head of aggF (both dead until after CSR build):
    u32*   binbuf  = (u32*)tG;                       // P1B*NBIN*CAP u32 = 12.8 MB < 16 MB
    float* out     = (float*)d_out;

    const dim3 blk256(256), blk192(192), blk96(96);
    const int GRID_FC    = (Nn + 63) / 64;           // 782
    const int GRID_AGG32 = (Nn + 63) / 64;           // 782 (64 nodes/block)
    const int GRID_AGG96 = (Nn + 15) / 16;           // 3125
    const int GRID_POOL  = (Nn + PCHUNK - 1) / PCHUNK;

    // ----- x -> bf16 -----
    x2bf_kernel<<<GRID_FC, blk256, 0, stream>>>(x, xb);

    // ----- Build CSR (binned two-level sort; no global atomics) -----
    p1_bin_kernel<<<P1B, blk256, 0, stream>>>(src, dst, binbuf, counts);
    p2_binscan_kernel<<<1, blk256, 0, stream>>>(counts, binbase, rowptr);
    p3_binsort_kernel<<<NBIN, blk256, 0, stream>>>(binbuf, counts, binbase, rowptr, csr);

    // ----- Layer 1: agg32(xb)->aggF ; fc1(aggF)->tG ; fc2(tG)->tA -----
    agg32_bf16_kernel<<<GRID_AGG32, blk256, 0, stream>>>(xb, rowptr, csr, aggF);
    fc_kernel<INF, true, false, true><<<GRID_FC, blk256, 0, stream>>>(aggF,
        P[0][0], P[0][1], P[0][2], P[0][3], P[0][4], P[0][5], tG);
    fc_kernel<Hh, false, true, true><<<GRID_FC, blk256, 0, stream>>>(tG,
        P[0][6], P[0][7], nullptr, nullptr, nullptr, nullptr, tA);

    // ----- Layer 2: agg96(tA)->tG ; fc1 in-place tG ; fc2(tG)->tB -----
    agg_csr_bf16_kernel<<<GRID_AGG96, blk192, 0, stream>>>(tA, rowptr, csr, tG);
    fc_kernel<Hh, true, true, true><<<GRID_FC, blk256, 0, stream>>>(tG,
        P[1][0], P[1][1], P[1][2], P[1][3], P[1][4], P[1][5], tG);
    fc_kernel<Hh, false, true, true><<<GRID_FC, blk256, 0, stream>>>(tG,
        P[1][6], P[1][7], nullptr, nullptr, nullptr, nullptr, tB);

    // ----- Layer 3: agg96(tB)->tG ; fc1 in-place tG ; fc2(tG)->tA -----
    agg_csr_bf16_kernel<<<GRID_AGG96, blk192, 0, stream>>>(tB, rowptr, csr, tG);
    fc_kernel<Hh, true, true, true><<<GRID_FC, blk256, 0, stream>>>(tG,
        P[2][0], P[2][1], P[2][2], P[2][3], P[2][4], P[2][5], tG);
    fc_kernel<Hh, false, true, true><<<GRID_FC, blk256, 0, stream>>>(tG,
        P[2][6], P[2][7], nullptr, nullptr, nullptr, nullptr, tA);

    // ----- Pool (chunked) + head -----
    hipMemsetAsync(pooled, 0, (size_t)Bb * Hh * sizeof(float), stream);
    pool_kernel<<<GRID_POOL, blk96, 0, stream>>>(tA, batch, pooled);
    head_kernel<<<Bb, 64, 0, stream>>>(pooled, rt, head_w, head_b, out);
}

// Round 8
// 296.603 us; speedup vs baseline: 3.5314x; 1.0096x over previous
//
#include <hip/hip_runtime.h>

using u16 = unsigned short;
using u32 = unsigned int;

// Problem constants (from reference)
constexpr int Nn  = 50000;   // nodes
constexpr int Ee  = 800000;  // edges
constexpr int Bb  = 256;     // graphs
constexpr int INF = 32;      // input feature dim
constexpr int Hh  = 96;      // hidden dim
constexpr float BN_EPS = 1e-5f;

// Binned CSR build parameters
constexpr int BINW = 256;                      // nodes per bin
constexpr int NBIN = (Nn + BINW - 1) / BINW;   // 196
constexpr int P1B  = 256;                      // pass-1 blocks
constexpr int EPB  = Ee / P1B;                 // 3125 edges per block (exact)
constexpr int CAP  = 64;                       // per (block,bin) capacity (mean 16, 12 sigma)

// ---------------- bf16 helpers (rne) ----------------
__device__ __forceinline__ float bfL(u32 u) { return __uint_as_float(u << 16); }
__device__ __forceinline__ float bfH(u32 u) { return __uint_as_float(u & 0xFFFF0000u); }
__device__ __forceinline__ u32 f2bfb(float f) {            // rounded bf16 bits (low 16)
    u32 b = __float_as_uint(f);
    return (b + 0x7FFFu + ((b >> 16) & 1u)) >> 16;
}
__device__ __forceinline__ float bf2f(u16 u) { return __uint_as_float(((u32)u) << 16); }

// ---------------------------------------------------------------------------
// x -> bf16 table (N x 32)
// ---------------------------------------------------------------------------
__global__ void x2bf_kernel(const float* __restrict__ x, u16* __restrict__ xb) {
    const int total = Nn * INF / 8;
    for (int i = blockIdx.x * 256 + threadIdx.x; i < total; i += gridDim.x * 256) {
        const float4 a = ((const float4*)x)[2 * i];
        const float4 b = ((const float4*)x)[2 * i + 1];
        uint4 R;
        R.x = f2bfb(a.x) | (f2bfb(a.y) << 16);
        R.y = f2bfb(a.z) | (f2bfb(a.w) << 16);
        R.z = f2bfb(b.x) | (f2bfb(b.y) << 16);
        R.w = f2bfb(b.z) | (f2bfb(b.w) << 16);
        ((uint4*)xb)[i] = R;
    }
}

// ---------------------------------------------------------------------------
// CSR build pass 1: bin edges into per-(block,bin) private regions.
// ---------------------------------------------------------------------------
__global__ __launch_bounds__(256)
void p1_bin_kernel(const int* __restrict__ src, const int* __restrict__ dst,
                   u32* __restrict__ binbuf, int* __restrict__ counts) {
    __shared__ int cur[NBIN];
    const int b = blockIdx.x, tid = threadIdx.x;
    for (int k = tid; k < NBIN; k += 256) cur[k] = 0;
    __syncthreads();
    const long e0 = (long)b * EPB;
    for (int i = tid; i < EPB; i += 256) {
        const long e = e0 + i;
        const int d = dst[e];
        const int k = d >> 8;
        const int pos = atomicAdd(&cur[k], 1);
        binbuf[((long)b * NBIN + k) * CAP + pos] = ((u32)(d & 255) << 16) | (u32)src[e];
    }
    __syncthreads();
    for (int k = tid; k < NBIN; k += 256) counts[k * P1B + b] = cur[k];
}

// ---------------------------------------------------------------------------
// CSR build pass 2: bin totals -> exclusive prefix (binbase); rowptr[N] = E.
// ---------------------------------------------------------------------------
__global__ void p2_binscan_kernel(const int* __restrict__ counts, int* __restrict__ binbase,
                                  int* __restrict__ rowptr) {
    __shared__ int ps[256];
    const int t = threadIdx.x;
    int tot = 0;
    if (t < NBIN) {
        const int* cp = counts + t * P1B;
        for (int b = 0; b < P1B; ++b) tot += cp[b];
    }
    ps[t] = tot;
    __syncthreads();
    for (int d = 1; d < 256; d <<= 1) {
        int u = (t >= d) ? ps[t - d] : 0;
        __syncthreads();
        if (t >= d) ps[t] += u;
        __syncthreads();
    }
    if (t < NBIN) binbase[t] = ps[t] - tot;   // exclusive prefix
    if (t == 0) rowptr[Nn] = Ee;
}

// ---------------------------------------------------------------------------
// CSR build pass 3: one block per bin -> rowptr slice + sorted u16 csr window.
// ---------------------------------------------------------------------------
__global__ __launch_bounds__(256)
void p3_binsort_kernel(const u32* __restrict__ binbuf, const int* __restrict__ counts,
                       const int* __restrict__ binbase, int* __restrict__ rowptr,
                       u16* __restrict__ csr) {
    __shared__ int cnt[P1B];
    __shared__ int lhist[BINW];
    __shared__ int lpref[BINW];
    const int k = blockIdx.x, tid = threadIdx.x;

    for (int b = tid; b < P1B; b += 256) cnt[b] = counts[k * P1B + b];
    lhist[tid] = 0;
    __syncthreads();

    for (int flat = tid; flat < P1B * CAP; flat += 256) {
        const int b = flat / CAP, i = flat % CAP;
        if (i < cnt[b])
            atomicAdd(&lhist[binbuf[((long)b * NBIN + k) * CAP + i] >> 16], 1);
    }
    __syncthreads();

    const int v = lhist[tid];
    lpref[tid] = v;
    __syncthreads();
    for (int d = 1; d < 256; d <<= 1) {
        int u = (tid >= d) ? lpref[tid - d] : 0;
        __syncthreads();
        if (tid >= d) lpref[tid] += u;
        __syncthreads();
    }
    lpref[tid] -= v;

    const int base = binbase[k];
    const int node = k * BINW + tid;
    if (node < Nn) rowptr[node] = base + lpref[tid];
    lhist[tid] = 0;                         // reuse as cursor
    __syncthreads();

    for (int flat = tid; flat < P1B * CAP; flat += 256) {
        const int b = flat / CAP, i = flat % CAP;
        if (i < cnt[b]) {
            const u32 pv = binbuf[((long)b * NBIN + k) * CAP + i];
            const int dl = pv >> 16;
            const int pos = base + lpref[dl] + atomicAdd(&lhist[dl], 1);
            csr[pos] = (u16)(pv & 0xFFFFu);
        }
    }
}

// ---------------------------------------------------------------------------
// FUSED agg + FC1 + BN + ReLU.
// Gather phase: 4 threads per node accumulate self + neighbors (fp32) from the
// bf16 table directly into the LDS x-tile. GEMM phase: 64x96 register-blocked.
// out (bf16) never aliases hsrc.
// ---------------------------------------------------------------------------
template<int DIN>
__global__ __launch_bounds__(256)
void fused_agg_fc1_kernel(const u16* __restrict__ hsrc, const int* __restrict__ rowptr,
                          const u16* __restrict__ csr, const float* __restrict__ w,
                          const float* __restrict__ b_in,
                          const float* __restrict__ gamma, const float* __restrict__ beta,
                          const float* __restrict__ rmean, const float* __restrict__ rvar,
                          u16* __restrict__ out) {
    constexpr int RU4 = DIN / 8;              // uint4 per row
    constexpr int S   = RU4 / 4;              // row slots per thread (1 or 3)
    constexpr int XST = DIN + 4;
    __shared__ float ws[DIN * Hh];
    __shared__ float xs[64 * XST];

    const int tid = threadIdx.x;
    const int nbase = blockIdx.x * 64;

    // stage weights [DIN x 96]
    for (int i = tid * 4; i < DIN * Hh; i += 1024)
        *(float4*)&ws[i] = *(const float4*)&w[i];

    // gather: node = nbase + (tid>>2), lane ln covers columns [(s*4+ln)*8, +8)
    {
        const int grp = tid >> 2, ln = tid & 3;
        const int node = nbase + grp;
        if (node < Nn) {
            const uint4* h4 = (const uint4*)hsrc;
            float a[S][8];
            #pragma unroll
            for (int s = 0; s < S; ++s) {
                const uint4 U = h4[(long)node * RU4 + s * 4 + ln];
                a[s][0] = bfL(U.x); a[s][1] = bfH(U.x); a[s][2] = bfL(U.y); a[s][3] = bfH(U.y);
                a[s][4] = bfL(U.z); a[s][5] = bfH(U.z); a[s][6] = bfL(U.w); a[s][7] = bfH(U.w);
            }
            const int e0 = rowptr[node], e1 = rowptr[node + 1];
            for (int e = e0; e < e1; ++e) {
                const long sr = csr[e];
                #pragma unroll
                for (int s = 0; s < S; ++s) {
                    const uint4 U = h4[sr * RU4 + s * 4 + ln];
                    a[s][0] += bfL(U.x); a[s][1] += bfH(U.x); a[s][2] += bfL(U.y); a[s][3] += bfH(U.y);
                    a[s][4] += bfL(U.z); a[s][5] += bfH(U.z); a[s][6] += bfL(U.w); a[s][7] += bfH(U.w);
                }
            }
            #pragma unroll
            for (int s = 0; s < S; ++s) {
                float* xp = &xs[grp * XST + (s * 4 + ln) * 8];
                #pragma unroll
                for (int q = 0; q < 8; ++q) xp[q] = a[s][q];
            }
        }
    }

    // BN epilogue constants
    const int jt = tid & 15, nt = tid >> 4;
    const int j0 = jt * 6;
    float A[6], C[6];
    #pragma unroll
    for (int ji = 0; ji < 6; ++ji) {
        const int j = j0 + ji;
        const float s = gamma[j] * rsqrtf(rvar[j] + BN_EPS);
        A[ji] = s;
        C[ji] = (b_in[j] - rmean[j]) * s + beta[j];
    }
    __syncthreads();

    float acc[4][6] = {};
    #pragma unroll 4
    for (int k = 0; k < DIN; ++k) {
        float xv[4];
        #pragma unroll
        for (int ni = 0; ni < 4; ++ni) xv[ni] = xs[(nt * 4 + ni) * XST + k];
        float wv[6];
        #pragma unroll
        for (int q = 0; q < 3; ++q) {
            const float2 t = *(const float2*)&ws[k * Hh + j0 + 2 * q];
            wv[2 * q] = t.x; wv[2 * q + 1] = t.y;
        }
        #pragma unroll
        for (int ni = 0; ni < 4; ++ni)
            #pragma unroll
            for (int ji = 0; ji < 6; ++ji)
                acc[ni][ji] = fmaf(xv[ni], wv[ji], acc[ni][ji]);
    }

    #pragma unroll
    for (int ni = 0; ni < 4; ++ni) {
        const int node = nbase + nt * 4 + ni;
        if (node < Nn) {
            u16* op = out + (long)node * Hh + j0;
            #pragma unroll
            for (int q = 0; q < 3; ++q) {
                const float r0 = fmaxf(fmaf(acc[ni][2 * q],     A[2 * q],     C[2 * q]),     0.0f);
                const float r1 = fmaxf(fmaf(acc[ni][2 * q + 1], A[2 * q + 1], C[2 * q + 1]), 0.0f);
                *(u32*)(op + 2 * q) = f2bfb(r0) | (f2bfb(r1) << 16);
            }
        }
    }
}

// ---------------------------------------------------------------------------
// FC2 + ReLU (bf16 in/out), register-blocked. In-place safe.
// ---------------------------------------------------------------------------
__global__ __launch_bounds__(256)
void fc2_kernel(const u16* __restrict__ xin, const float* __restrict__ w,
                const float* __restrict__ b_out, u16* __restrict__ out) {
    constexpr int DIN = Hh;
    constexpr int XST = DIN + 4;
    __shared__ float ws[DIN * Hh];
    __shared__ float xs[64 * XST];

    const int tid = threadIdx.x;
    const int jt  = tid & 15;
    const int nt  = tid >> 4;
    const int j0  = jt * 6;
    const int nbase = blockIdx.x * 64;

    for (int i = tid * 4; i < DIN * Hh; i += 1024)
        *(float4*)&ws[i] = *(const float4*)&w[i];

    for (int idx = tid; idx < 64 * (DIN / 8); idx += 256) {
        const int r = idx / (DIN / 8), c = idx % (DIN / 8);
        const int gr = nbase + r;
        uint4 U = make_uint4(0u, 0u, 0u, 0u);
        if (gr < Nn) U = ((const uint4*)(xin + (long)gr * DIN))[c];
        float* xp = &xs[r * XST + c * 8];
        xp[0] = bfL(U.x); xp[1] = bfH(U.x); xp[2] = bfL(U.y); xp[3] = bfH(U.y);
        xp[4] = bfL(U.z); xp[5] = bfH(U.z); xp[6] = bfL(U.w); xp[7] = bfH(U.w);
    }

    float C[6];
    #pragma unroll
    for (int ji = 0; ji < 6; ++ji) C[ji] = b_out[j0 + ji];
    __syncthreads();

    float acc[4][6] = {};
    #pragma unroll 4
    for (int k = 0; k < DIN; ++k) {
        float xv[4];
        #pragma unroll
        for (int ni = 0; ni < 4; ++ni) xv[ni] = xs[(nt * 4 + ni) * XST + k];
        float wv[6];
        #pragma unroll
        for (int q = 0; q < 3; ++q) {
            const float2 t = *(const float2*)&ws[k * Hh + j0 + 2 * q];
            wv[2 * q] = t.x; wv[2 * q + 1] = t.y;
        }
        #pragma unroll
        for (int ni = 0; ni < 4; ++ni)
            #pragma unroll
            for (int ji = 0; ji < 6; ++ji)
                acc[ni][ji] = fmaf(xv[ni], wv[ji], acc[ni][ji]);
    }

    #pragma unroll
    for (int ni = 0; ni < 4; ++ni) {
        const int node = nbase + nt * 4 + ni;
        if (node < Nn) {
            u16* op = out + (long)node * Hh + j0;
            #pragma unroll
            for (int q = 0; q < 3; ++q) {
                const float r0 = fmaxf(acc[ni][2 * q]     + C[2 * q],     0.0f);
                const float r1 = fmaxf(acc[ni][2 * q + 1] + C[2 * q + 1], 0.0f);
                *(u32*)(op + 2 * q) = f2bfb(r0) | (f2bfb(r1) << 16);
            }
        }
    }
}

// ---------------------------------------------------------------------------
// Chunked pooling over bf16 table (batch sorted; boundary-flush atomics)
// ---------------------------------------------------------------------------
constexpr int PCHUNK = 64;
__global__ void pool_kernel(const u16* __restrict__ h, const int* __restrict__ batch,
                            float* __restrict__ pooled) {
    const int j = threadIdx.x;                 // 0..95
    const int c0 = blockIdx.x * PCHUNK;
    const int c1 = min(c0 + PCHUNK, Nn);
    if (c0 >= Nn) return;

    int bcur = batch[c0];
    float acc = 0.0f;
    for (int n = c0; n < c1; ++n) {
        const int bb = batch[n];
        if (bb != bcur) {
            atomicAdd(&pooled[(long)bcur * Hh + j], acc);
            acc = 0.0f;
            bcur = bb;
        }
        acc += bf2f(h[(long)n * Hh + j]);
    }
    atomicAdd(&pooled[(long)bcur * Hh + j], acc);
}

// ---------------------------------------------------------------------------
// Head: out[b] = dot(pooled[b], head_w[rt[b]]) + head_b[rt[b]]
// ---------------------------------------------------------------------------
__global__ void head_kernel(const float* __restrict__ pooled, const int* __restrict__ rt,
                            const float* __restrict__ hw, const float* __restrict__ hb,
                            float* __restrict__ outv) {
    const int b = blockIdx.x;
    const int lane = threadIdx.x;
    const int t = rt[b];
    const float* pp = pooled + (long)b * Hh;
    const float* wp = hw + (long)t * Hh;
    float s = 0.0f;
    for (int j = lane; j < Hh; j += 64) s += pp[j] * wp[j];
    #pragma unroll
    for (int off = 32; off > 0; off >>= 1) s += __shfl_down(s, off, 64);
    if (lane == 0) outv[b] = s + hb[t];
}

// ---------------------------------------------------------------------------
extern "C" void kernel_launch(void* const* d_in, const int* in_sizes, int n_in,
                              void* d_out, int out_size, void* d_ws, size_t ws_size,
                              hipStream_t stream) {
    const float* x     = (const float*)d_in[0];
    const int*   ei    = (const int*)d_in[1];      // [2, E] flattened int32
    const int*   src   = ei;
    const int*   dst   = ei + Ee;
    const int*   batch = (const int*)d_in[2];
    const int*   rt    = (const int*)d_in[3];

    const float* P[3][8];
    for (int l = 0; l < 3; ++l)
        for (int p = 0; p < 8; ++p)
            P[l][p] = (const float*)d_in[4 + l * 8 + p];
    const float* head_w = (const float*)d_in[28];
    const float* head_b = (const float*)d_in[29];

    // Workspace layout
    const size_t NH = (size_t)Nn * Hh;
    u16*   tA      = (u16*)d_ws;                       // N*H bf16
    u16*   tB      = tA + NH;                          // N*H bf16
    u16*   tG      = tB + NH;                          // N*H bf16
    u16*   xb      = tG + NH;                          // N*INF bf16
    float* pooled  = (float*)(xb + (size_t)Nn * INF);  // B*H fp32
    int*   rowptr  = (int*)(pooled + (size_t)Bb * Hh); // N+1 ints
    int*   counts  = rowptr + Nn + 1;                  // NBIN*P1B ints
    int*   binbase = counts + NBIN * P1B;              // NBIN ints
    u16*   csr     = (u16*)(binbase + NBIN);           // E u16
    // binbuf (12.8 MB) overlays tA+tB (19.2 MB) — both dead during CSR build
    u32*   binbuf  = (u32*)tA;
    float* out     = (float*)d_out;

    const dim3 blk256(256), blk96(96);
    const int GRID_T    = (Nn + 63) / 64;              // 782 tiles
    const int GRID_POOL = (Nn + PCHUNK - 1) / PCHUNK;

    // ----- x -> bf16 ; build CSR (binned two-level sort) -----
    x2bf_kernel<<<GRID_T, blk256, 0, stream>>>(x, xb);
    p1_bin_kernel<<<P1B, blk256, 0, stream>>>(src, dst, binbuf, counts);
    p2_binscan_kernel<<<1, blk256, 0, stream>>>(counts, binbase, rowptr);
    p3_binsort_kernel<<<NBIN, blk256, 0, stream>>>(binbuf, counts, binbase, rowptr, csr);

    // ----- Layer 1: fused agg+fc1(xb) -> tG ; fc2 -> tA -----
    fused_agg_fc1_kernel<INF><<<GRID_T, blk256, 0, stream>>>(xb, rowptr, csr,
        P[0][0], P[0][1], P[0][2], P[0][3], P[0][4], P[0][5], tG);
    fc2_kernel<<<GRID_T, blk256, 0, stream>>>(tG, P[0][6], P[0][7], tA);

    // ----- Layer 2: fused agg+fc1(tA) -> tG ; fc2 -> tB -----
    fused_agg_fc1_kernel<Hh><<<GRID_T, blk256, 0, stream>>>(tA, rowptr, csr,
        P[1][0], P[1][1], P[1][2], P[1][3], P[1][4], P[1][5], tG);
    fc2_kernel<<<GRID_T, blk256, 0, stream>>>(tG, P[1][6], P[1][7], tB);

    // ----- Layer 3: fused agg+fc1(tB) -> tG ; fc2 -> tA -----
    fused_agg_fc1_kernel<Hh><<<GRID_T, blk256, 0, stream>>>(tB, rowptr, csr,
        P[2][0], P[2][1], P[2][2], P[2][3], P[2][4], P[2][5], tG);
    fc2_kernel<<<GRID_T, blk256, 0, stream>>>(tG, P[2][6], P[2][7], tA);

    // ----- Pool (chunked) + head -----
    hipMemsetAsync(pooled, 0, (size_t)Bb * Hh * sizeof(float), stream);
    pool_kernel<<<GRID_POOL, blk96, 0, stream>>>(tA, batch, pooled);
    head_kernel<<<Bb, 64, 0, stream>>>(pooled, rt, head_w, head_b, out);
}

// Round 9
// 278.587 us; speedup vs baseline: 3.7598x; 1.0647x over previous
//
#include <hip/hip_runtime.h>

using u16 = unsigned short;
using u32 = unsigned int;

// Problem constants (from reference)
constexpr int Nn  = 50000;   // nodes
constexpr int Ee  = 800000;  // edges
constexpr int Bb  = 256;     // graphs
constexpr int INF = 32;      // input feature dim
constexpr int Hh  = 96;      // hidden dim
constexpr float BN_EPS = 1e-5f;

// Binned CSR build parameters
constexpr int BINW = 256;                      // nodes per bin
constexpr int NBIN = (Nn + BINW - 1) / BINW;   // 196
constexpr int P1B  = 256;                      // pass-1 blocks
constexpr int EPB  = Ee / P1B;                 // 3125 edges per block (exact)
constexpr int CAP  = 64;                       // per (block,bin) capacity (mean 16, 12 sigma)

// ---------------- bf16 helpers (rne) ----------------
__device__ __forceinline__ float bfL(u32 u) { return __uint_as_float(u << 16); }
__device__ __forceinline__ float bfH(u32 u) { return __uint_as_float(u & 0xFFFF0000u); }
__device__ __forceinline__ u32 f2bfb(float f) {            // rounded bf16 bits (low 16)
    u32 b = __float_as_uint(f);
    return (b + 0x7FFFu + ((b >> 16) & 1u)) >> 16;
}
__device__ __forceinline__ float bf2f(u16 u) { return __uint_as_float(((u32)u) << 16); }

// ---------------------------------------------------------------------------
// x -> bf16 table (N x 32)
// ---------------------------------------------------------------------------
__global__ void x2bf_kernel(const float* __restrict__ x, u16* __restrict__ xb) {
    const int total = Nn * INF / 8;
    for (int i = blockIdx.x * 256 + threadIdx.x; i < total; i += gridDim.x * 256) {
        const float4 a = ((const float4*)x)[2 * i];
        const float4 b = ((const float4*)x)[2 * i + 1];
        uint4 R;
        R.x = f2bfb(a.x) | (f2bfb(a.y) << 16);
        R.y = f2bfb(a.z) | (f2bfb(a.w) << 16);
        R.z = f2bfb(b.x) | (f2bfb(b.y) << 16);
        R.w = f2bfb(b.z) | (f2bfb(b.w) << 16);
        ((uint4*)xb)[i] = R;
    }
}

// ---------------------------------------------------------------------------
// CSR build pass 1: bin edges into per-(block,bin) private regions.
// ---------------------------------------------------------------------------
__global__ __launch_bounds__(256)
void p1_bin_kernel(const int* __restrict__ src, const int* __restrict__ dst,
                   u32* __restrict__ binbuf, int* __restrict__ counts) {
    __shared__ int cur[NBIN];
    const int b = blockIdx.x, tid = threadIdx.x;
    for (int k = tid; k < NBIN; k += 256) cur[k] = 0;
    __syncthreads();
    const long e0 = (long)b * EPB;
    for (int i = tid; i < EPB; i += 256) {
        const long e = e0 + i;
        const int d = dst[e];
        const int k = d >> 8;
        const int pos = atomicAdd(&cur[k], 1);
        binbuf[((long)b * NBIN + k) * CAP + pos] = ((u32)(d & 255) << 16) | (u32)src[e];
    }
    __syncthreads();
    for (int k = tid; k < NBIN; k += 256) counts[k * P1B + b] = cur[k];
}

// ---------------------------------------------------------------------------
// CSR build pass 2: bin totals -> exclusive prefix (binbase); rowptr[N] = E.
// ---------------------------------------------------------------------------
__global__ void p2_binscan_kernel(const int* __restrict__ counts, int* __restrict__ binbase,
                                  int* __restrict__ rowptr) {
    __shared__ int ps[256];
    const int t = threadIdx.x;
    int tot = 0;
    if (t < NBIN) {
        const int* cp = counts + t * P1B;
        for (int b = 0; b < P1B; ++b) tot += cp[b];
    }
    ps[t] = tot;
    __syncthreads();
    for (int d = 1; d < 256; d <<= 1) {
        int u = (t >= d) ? ps[t - d] : 0;
        __syncthreads();
        if (t >= d) ps[t] += u;
        __syncthreads();
    }
    if (t < NBIN) binbase[t] = ps[t] - tot;   // exclusive prefix
    if (t == 0) rowptr[Nn] = Ee;
}

// ---------------------------------------------------------------------------
// CSR build pass 3: one block per bin -> rowptr slice + sorted u16 csr window.
// ---------------------------------------------------------------------------
__global__ __launch_bounds__(256)
void p3_binsort_kernel(const u32* __restrict__ binbuf, const int* __restrict__ counts,
                       const int* __restrict__ binbase, int* __restrict__ rowptr,
                       u16* __restrict__ csr) {
    __shared__ int cnt[P1B];
    __shared__ int lhist[BINW];
    __shared__ int lpref[BINW];
    const int k = blockIdx.x, tid = threadIdx.x;

    for (int b = tid; b < P1B; b += 256) cnt[b] = counts[k * P1B + b];
    lhist[tid] = 0;
    __syncthreads();

    for (int flat = tid; flat < P1B * CAP; flat += 256) {
        const int b = flat / CAP, i = flat % CAP;
        if (i < cnt[b])
            atomicAdd(&lhist[binbuf[((long)b * NBIN + k) * CAP + i] >> 16], 1);
    }
    __syncthreads();

    const int v = lhist[tid];
    lpref[tid] = v;
    __syncthreads();
    for (int d = 1; d < 256; d <<= 1) {
        int u = (tid >= d) ? lpref[tid - d] : 0;
        __syncthreads();
        if (tid >= d) lpref[tid] += u;
        __syncthreads();
    }
    lpref[tid] -= v;

    const int base = binbase[k];
    const int node = k * BINW + tid;
    if (node < Nn) rowptr[node] = base + lpref[tid];
    lhist[tid] = 0;                         // reuse as cursor
    __syncthreads();

    for (int flat = tid; flat < P1B * CAP; flat += 256) {
        const int b = flat / CAP, i = flat % CAP;
        if (i < cnt[b]) {
            const u32 pv = binbuf[((long)b * NBIN + k) * CAP + i];
            const int dl = pv >> 16;
            const int pos = base + lpref[dl] + atomicAdd(&lhist[dl], 1);
            csr[pos] = (u16)(pv & 0xFFFFu);
        }
    }
}

// ---------------------------------------------------------------------------
// FUSED agg + FC1 + BN + ReLU.
// Gather: 4 threads/node accumulate self+neighbors (fp32) with 2x-unrolled
// edge loop, deposit bf16 into LDS x-tile. GEMM: 64x96 register-blocked,
// consuming k-pairs (u32 = 2 bf16). xs stride DIN+2 keeps reads 2-way-free.
// ---------------------------------------------------------------------------
template<int DIN>
__global__ __launch_bounds__(256)
void fused_agg_fc1_kernel(const u16* __restrict__ hsrc, const int* __restrict__ rowptr,
                          const u16* __restrict__ csr, const float* __restrict__ w,
                          const float* __restrict__ b_in,
                          const float* __restrict__ gamma, const float* __restrict__ beta,
                          const float* __restrict__ rmean, const float* __restrict__ rvar,
                          u16* __restrict__ out) {
    constexpr int RU4  = DIN / 8;             // uint4 per row (4 or 12)
    constexpr int S    = RU4 / 4;             // row slots per thread (1 or 3)
    constexpr int XSTU = DIN + 2;             // u16 stride (34 or 98)
    __shared__ float ws[DIN * Hh];
    __shared__ u16 xs[64 * XSTU];

    const int tid = threadIdx.x;
    const int nbase = blockIdx.x * 64;

    // stage weights [DIN x 96] fp32
    for (int i = tid * 4; i < DIN * Hh; i += 1024)
        *(float4*)&ws[i] = *(const float4*)&w[i];

    // gather: node = nbase + (tid>>2), lane ln covers columns [(s*4+ln)*8, +8)
    {
        const int grp = tid >> 2, ln = tid & 3;
        const int node = nbase + grp;
        if (node < Nn) {
            const uint4* h4 = (const uint4*)hsrc;
            float a[S][8];
            #pragma unroll
            for (int s = 0; s < S; ++s) {
                const uint4 U = h4[(long)node * RU4 + s * 4 + ln];
                a[s][0] = bfL(U.x); a[s][1] = bfH(U.x); a[s][2] = bfL(U.y); a[s][3] = bfH(U.y);
                a[s][4] = bfL(U.z); a[s][5] = bfH(U.z); a[s][6] = bfL(U.w); a[s][7] = bfH(U.w);
            }
            const int e0 = rowptr[node], e1 = rowptr[node + 1];
            int e = e0;
            for (; e + 2 <= e1; e += 2) {                  // 2x unroll: 2S loads in flight
                const long s0 = csr[e], s1 = csr[e + 1];
                uint4 U0[S], U1[S];
                #pragma unroll
                for (int s = 0; s < S; ++s) U0[s] = h4[s0 * RU4 + s * 4 + ln];
                #pragma unroll
                for (int s = 0; s < S; ++s) U1[s] = h4[s1 * RU4 + s * 4 + ln];
                #pragma unroll
                for (int s = 0; s < S; ++s) {
                    a[s][0] += bfL(U0[s].x); a[s][1] += bfH(U0[s].x);
                    a[s][2] += bfL(U0[s].y); a[s][3] += bfH(U0[s].y);
                    a[s][4] += bfL(U0[s].z); a[s][5] += bfH(U0[s].z);
                    a[s][6] += bfL(U0[s].w); a[s][7] += bfH(U0[s].w);
                    a[s][0] += bfL(U1[s].x); a[s][1] += bfH(U1[s].x);
                    a[s][2] += bfL(U1[s].y); a[s][3] += bfH(U1[s].y);
                    a[s][4] += bfL(U1[s].z); a[s][5] += bfH(U1[s].z);
                    a[s][6] += bfL(U1[s].w); a[s][7] += bfH(U1[s].w);
                }
            }
            if (e < e1) {
                const long s0 = csr[e];
                #pragma unroll
                for (int s = 0; s < S; ++s) {
                    const uint4 U = h4[s0 * RU4 + s * 4 + ln];
                    a[s][0] += bfL(U.x); a[s][1] += bfH(U.x);
                    a[s][2] += bfL(U.y); a[s][3] += bfH(U.y);
                    a[s][4] += bfL(U.z); a[s][5] += bfH(U.z);
                    a[s][6] += bfL(U.w); a[s][7] += bfH(U.w);
                }
            }
            #pragma unroll
            for (int s = 0; s < S; ++s) {
                u32* xp = (u32*)&xs[grp * XSTU + (s * 4 + ln) * 8];
                #pragma unroll
                for (int q = 0; q < 4; ++q)
                    xp[q] = f2bfb(a[s][2 * q]) | (f2bfb(a[s][2 * q + 1]) << 16);
            }
        }
    }

    // BN epilogue constants
    const int jt = tid & 15, nt = tid >> 4;
    const int j0 = jt * 6;
    float A[6], C[6];
    #pragma unroll
    for (int ji = 0; ji < 6; ++ji) {
        const int j = j0 + ji;
        const float s = gamma[j] * rsqrtf(rvar[j] + BN_EPS);
        A[ji] = s;
        C[ji] = (b_in[j] - rmean[j]) * s + beta[j];
    }
    __syncthreads();

    float acc[4][6] = {};
    #pragma unroll 2
    for (int k2 = 0; k2 < DIN / 2; ++k2) {
        float xlo[4], xhi[4];
        #pragma unroll
        for (int ni = 0; ni < 4; ++ni) {
            const u32 xv = *(const u32*)&xs[(nt * 4 + ni) * XSTU + k2 * 2];
            xlo[ni] = bfL(xv); xhi[ni] = bfH(xv);
        }
        float wlo[6], whi[6];
        #pragma unroll
        for (int q = 0; q < 3; ++q) {
            const float2 t0 = *(const float2*)&ws[(2 * k2)     * Hh + j0 + 2 * q];
            const float2 t1 = *(const float2*)&ws[(2 * k2 + 1) * Hh + j0 + 2 * q];
            wlo[2 * q] = t0.x; wlo[2 * q + 1] = t0.y;
            whi[2 * q] = t1.x; whi[2 * q + 1] = t1.y;
        }
        #pragma unroll
        for (int ni = 0; ni < 4; ++ni)
            #pragma unroll
            for (int ji = 0; ji < 6; ++ji) {
                acc[ni][ji] = fmaf(xlo[ni], wlo[ji], acc[ni][ji]);
                acc[ni][ji] = fmaf(xhi[ni], whi[ji], acc[ni][ji]);
            }
    }

    #pragma unroll
    for (int ni = 0; ni < 4; ++ni) {
        const int node = nbase + nt * 4 + ni;
        if (node < Nn) {
            u16* op = out + (long)node * Hh + j0;
            #pragma unroll
            for (int q = 0; q < 3; ++q) {
                const float r0 = fmaxf(fmaf(acc[ni][2 * q],     A[2 * q],     C[2 * q]),     0.0f);
                const float r1 = fmaxf(fmaf(acc[ni][2 * q + 1], A[2 * q + 1], C[2 * q + 1]), 0.0f);
                *(u32*)(op + 2 * q) = f2bfb(r0) | (f2bfb(r1) << 16);
            }
        }
    }
}

// ---------------------------------------------------------------------------
// FC2 + ReLU (bf16 in/out), register-blocked, bf16 LDS x-tile.
// ---------------------------------------------------------------------------
__global__ __launch_bounds__(256)
void fc2_kernel(const u16* __restrict__ xin, const float* __restrict__ w,
                const float* __restrict__ b_out, u16* __restrict__ out) {
    constexpr int DIN  = Hh;
    constexpr int XSTU = DIN + 2;             // 98
    __shared__ float ws[DIN * Hh];
    __shared__ u16 xs[64 * XSTU];

    const int tid = threadIdx.x;
    const int jt  = tid & 15;
    const int nt  = tid >> 4;
    const int j0  = jt * 6;
    const int nbase = blockIdx.x * 64;

    for (int i = tid * 4; i < DIN * Hh; i += 1024)
        *(float4*)&ws[i] = *(const float4*)&w[i];

    // stage x tile raw bf16 (u32 stores to respect padded stride alignment)
    for (int idx = tid; idx < 64 * (DIN / 8); idx += 256) {
        const int r = idx / (DIN / 8), c = idx % (DIN / 8);
        const int gr = nbase + r;
        uint4 U = make_uint4(0u, 0u, 0u, 0u);
        if (gr < Nn) U = ((const uint4*)(xin + (long)gr * DIN))[c];
        u32* xp = (u32*)&xs[r * XSTU + c * 8];
        xp[0] = U.x; xp[1] = U.y; xp[2] = U.z; xp[3] = U.w;
    }

    float C[6];
    #pragma unroll
    for (int ji = 0; ji < 6; ++ji) C[ji] = b_out[j0 + ji];
    __syncthreads();

    float acc[4][6] = {};
    #pragma unroll 2
    for (int k2 = 0; k2 < DIN / 2; ++k2) {
        float xlo[4], xhi[4];
        #pragma unroll
        for (int ni = 0; ni < 4; ++ni) {
            const u32 xv = *(const u32*)&xs[(nt * 4 + ni) * XSTU + k2 * 2];
            xlo[ni] = bfL(xv); xhi[ni] = bfH(xv);
        }
        float wlo[6], whi[6];
        #pragma unroll
        for (int q = 0; q < 3; ++q) {
            const float2 t0 = *(const float2*)&ws[(2 * k2)     * Hh + j0 + 2 * q];
            const float2 t1 = *(const float2*)&ws[(2 * k2 + 1) * Hh + j0 + 2 * q];
            wlo[2 * q] = t0.x; wlo[2 * q + 1] = t0.y;
            whi[2 * q] = t1.x; whi[2 * q + 1] = t1.y;
        }
        #pragma unroll
        for (int ni = 0; ni < 4; ++ni)
            #pragma unroll
            for (int ji = 0; ji < 6; ++ji) {
                acc[ni][ji] = fmaf(xlo[ni], wlo[ji], acc[ni][ji]);
                acc[ni][ji] = fmaf(xhi[ni], whi[ji], acc[ni][ji]);
            }
    }

    #pragma unroll
    for (int ni = 0; ni < 4; ++ni) {
        const int node = nbase + nt * 4 + ni;
        if (node < Nn) {
            u16* op = out + (long)node * Hh + j0;
            #pragma unroll
            for (int q = 0; q < 3; ++q) {
                const float r0 = fmaxf(acc[ni][2 * q]     + C[2 * q],     0.0f);
                const float r1 = fmaxf(acc[ni][2 * q + 1] + C[2 * q + 1], 0.0f);
                *(u32*)(op + 2 * q) = f2bfb(r0) | (f2bfb(r1) << 16);
            }
        }
    }
}

// ---------------------------------------------------------------------------
// Chunked pooling over bf16 table (batch sorted; boundary-flush atomics)
// ---------------------------------------------------------------------------
constexpr int PCHUNK = 64;
__global__ void pool_kernel(const u16* __restrict__ h, const int* __restrict__ batch,
                            float* __restrict__ pooled) {
    const int j = threadIdx.x;                 // 0..95
    const int c0 = blockIdx.x * PCHUNK;
    const int c1 = min(c0 + PCHUNK, Nn);
    if (c0 >= Nn) return;

    int bcur = batch[c0];
    float acc = 0.0f;
    for (int n = c0; n < c1; ++n) {
        const int bb = batch[n];
        if (bb != bcur) {
            atomicAdd(&pooled[(long)bcur * Hh + j], acc);
            acc = 0.0f;
            bcur = bb;
        }
        acc += bf2f(h[(long)n * Hh + j]);
    }
    atomicAdd(&pooled[(long)bcur * Hh + j], acc);
}

// ---------------------------------------------------------------------------
// Head: out[b] = dot(pooled[b], head_w[rt[b]]) + head_b[rt[b]]
// ---------------------------------------------------------------------------
__global__ void head_kernel(const float* __restrict__ pooled, const int* __restrict__ rt,
                            const float* __restrict__ hw, const float* __restrict__ hb,
                            float* __restrict__ outv) {
    const int b = blockIdx.x;
    const int lane = threadIdx.x;
    const int t = rt[b];
    const float* pp = pooled + (long)b * Hh;
    const float* wp = hw + (long)t * Hh;
    float s = 0.0f;
    for (int j = lane; j < Hh; j += 64) s += pp[j] * wp[j];
    #pragma unroll
    for (int off = 32; off > 0; off >>= 1) s += __shfl_down(s, off, 64);
    if (lane == 0) outv[b] = s + hb[t];
}

// ---------------------------------------------------------------------------
extern "C" void kernel_launch(void* const* d_in, const int* in_sizes, int n_in,
                              void* d_out, int out_size, void* d_ws, size_t ws_size,
                              hipStream_t stream) {
    const float* x     = (const float*)d_in[0];
    const int*   ei    = (const int*)d_in[1];      // [2, E] flattened int32
    const int*   src   = ei;
    const int*   dst   = ei + Ee;
    const int*   batch = (const int*)d_in[2];
    const int*   rt    = (const int*)d_in[3];

    const float* P[3][8];
    for (int l = 0; l < 3; ++l)
        for (int p = 0; p < 8; ++p)
            P[l][p] = (const float*)d_in[4 + l * 8 + p];
    const float* head_w = (const float*)d_in[28];
    const float* head_b = (const float*)d_in[29];

    // Workspace layout
    const size_t NH = (size_t)Nn * Hh;
    u16*   tA      = (u16*)d_ws;                       // N*H bf16
    u16*   tB      = tA + NH;                          // N*H bf16
    u16*   tG      = tB + NH;                          // N*H bf16
    u16*   xb      = tG + NH;                          // N*INF bf16
    float* pooled  = (float*)(xb + (size_t)Nn * INF);  // B*H fp32
    int*   rowptr  = (int*)(pooled + (size_t)Bb * Hh); // N+1 ints
    int*   counts  = rowptr + Nn + 1;                  // NBIN*P1B ints
    int*   binbase = counts + NBIN * P1B;              // NBIN ints
    u16*   csr     = (u16*)(binbase + NBIN);           // E u16
    // binbuf (12.8 MB) overlays tA+tB (19.2 MB) — both dead during CSR build
    u32*   binbuf  = (u32*)tA;
    float* out     = (float*)d_out;

    const dim3 blk256(256), blk96(96);
    const int GRID_T    = (Nn + 63) / 64;              // 782 tiles
    const int GRID_POOL = (Nn + PCHUNK - 1) / PCHUNK;

    // ----- x -> bf16 ; build CSR (binned two-level sort) -----
    x2bf_kernel<<<GRID_T, blk256, 0, stream>>>(x, xb);
    p1_bin_kernel<<<P1B, blk256, 0, stream>>>(src, dst, binbuf, counts);
    p2_binscan_kernel<<<1, blk256, 0, stream>>>(counts, binbase, rowptr);
    p3_binsort_kernel<<<NBIN, blk256, 0, stream>>>(binbuf, counts, binbase, rowptr, csr);

    // ----- Layer 1: fused agg+fc1(xb) -> tG ; fc2 -> tA -----
    fused_agg_fc1_kernel<INF><<<GRID_T, blk256, 0, stream>>>(xb, rowptr, csr,
        P[0][0], P[0][1], P[0][2], P[0][3], P[0][4], P[0][5], tG);
    fc2_kernel<<<GRID_T, blk256, 0, stream>>>(tG, P[0][6], P[0][7], tA);

    // ----- Layer 2: fused agg+fc1(tA) -> tG ; fc2 -> tB -----
    fused_agg_fc1_kernel<Hh><<<GRID_T, blk256, 0, stream>>>(tA, rowptr, csr,
        P[1][0], P[1][1], P[1][2], P[1][3], P[1][4], P[1][5], tG);
    fc2_kernel<<<GRID_T, blk256, 0, stream>>>(tG, P[1][6], P[1][7], tB);

    // ----- Layer 3: fused agg+fc1(tB) -> tG ; fc2 -> tA -----
    fused_agg_fc1_kernel<Hh><<<GRID_T, blk256, 0, stream>>>(tB, rowptr, csr,
        P[2][0], P[2][1], P[2][2], P[2][3], P[2][4], P[2][5], tG);
    fc2_kernel<<<GRID_T, blk256, 0, stream>>>(tG, P[2][6], P[2][7], tA);

    // ----- Pool (chunked) + head -----
    hipMemsetAsync(pooled, 0, (size_t)Bb * Hh * sizeof(float), stream);
    pool_kernel<<<GRID_POOL, blk96, 0, stream>>>(tA, batch, pooled);
    head_kernel<<<Bb, 64, 0, stream>>>(pooled, rt, head_w, head_b, out);
}